// Round 19
// baseline (185.763 us; speedup 1.0000x reference)
//
#include <hip/hip_runtime.h>
#include <hip/hip_bf16.h>
#include <cmath>

namespace {
constexpr int B_ = 16, N_ = 307, T_ = 24, C_ = 128, H_ = 8, D_ = 16, S_ = 20, U_ = 20;
constexpr int NROW = B_ * N_ * T_;          // 117888
constexpr int NX = NROW * C_;               // 15089664
constexpr int TEPE_N = B_ * T_ * C_;        // 49152
constexpr int FF = 4 * C_;                  // 512
constexpr int BM = 32;                      // rows per qkv block
constexpr int NBLK_MM = NROW / BM;          // 3684
constexpr int BMT = 64;                     // rows per tail block (256 thr, 4 waves)
constexpr int NBLK_T = NROW / BMT;          // 1842
constexpr int NUNIT = B_ * H_ * N_;         // 39296
constexpr int PREP_N = TEPE_N + 384 * C_ + (2 * C_ * FF + C_ * C_);  // 245760
}

typedef __attribute__((ext_vector_type(8))) short short8;
typedef __attribute__((ext_vector_type(4))) short short4_;
typedef __attribute__((ext_vector_type(4))) float f32x4;

__device__ inline short f2bf(float v) {
    union { float f; unsigned u; } a; a.f = v;
    unsigned r = a.u + 0x7fff + ((a.u >> 16) & 1);   // round-to-nearest-even
    return (short)(r >> 16);
}
__device__ inline float bf2f(short s) {
    return __bfloat162float(*(const __hip_bfloat16*)&s);
}

// ---------------- kernel 0: merged prep — tepe + all weight converts + cnt table
__global__ void k_prep(const int* __restrict__ te,
                       const float* __restrict__ e_min, const float* __restrict__ e_hr,
                       const float* __restrict__ e_wd, const float* __restrict__ e_mo,
                       const float* __restrict__ e_yr, float* __restrict__ tepe,
                       const int* __restrict__ idxs, unsigned char* __restrict__ cntg,
                       const float* __restrict__ Wq, const float* __restrict__ Wk,
                       const float* __restrict__ Wv, short* __restrict__ wqkvf,
                       const float* __restrict__ w1, const float* __restrict__ w2,
                       const float* __restrict__ Wo,
                       short* __restrict__ w1f, short* __restrict__ w2f,
                       short* __restrict__ wof) {
    int i = blockIdx.x * 256 + threadIdx.x;
    if (i < TEPE_N) {
        int c = i & (C_ - 1);
        int bt = i >> 7;              // b*T + t
        int t = bt % T_;
        const int* enc = te + bt * 5;
        float v = e_min[enc[0] * C_ + c] + e_hr[enc[1] * C_ + c] + e_wd[enc[2] * C_ + c]
                + e_mo[enc[3] * C_ + c] + e_yr[enc[4] * C_ + c];
        float ang = (float)t * expf(-(float)(c & ~1) * (9.210340371976184f / 128.0f));
        v += (c & 1) ? cosf(ang) : sinf(ang);
        tepe[i] = v;
    } else if (i < TEPE_N + 384 * C_) {
        int j = i - TEPE_N;                 // wqkvf, frag-linear
        int tile = j >> 9, l = (j >> 3) & 63, e = j & 7;
        int c_tile = tile >> 2, ks = tile & 3;
        int c_all = c_tile * 16 + (l & 15);
        int k = ks * 32 + (l >> 4) * 8 + e;
        int m = c_all >> 7, c = c_all & (C_ - 1);
        const float* W = (m == 0) ? Wq : (m == 1) ? Wk : Wv;
        wqkvf[j] = f2bf(W[k * C_ + c]);
    } else {
        int j = i - TEPE_N - 384 * C_;      // w1f / w2f / wof, frag-linear
        if (j < C_ * FF) {
            int tile = j >> 9, l = (j >> 3) & 63, e = j & 7;
            int jtile = tile >> 2, ks = tile & 3;
            int jj = jtile * 16 + (l & 15);
            int k = ks * 32 + (l >> 4) * 8 + e;
            w1f[j] = f2bf(w1[k * FF + jj]);
        } else if (j < 2 * C_ * FF) {
            int j2 = j - C_ * FF;
            int tile = j2 >> 9, l = (j2 >> 3) & 63, e = j2 & 7;
            int c_tile = tile >> 4, ks = tile & 15;
            int c = c_tile * 16 + (l & 15);
            int jj = ks * 32 + (l >> 4) * 8 + e;
            w2f[j2] = f2bf(w2[jj * C_ + c]);
        } else {
            int j3 = j - 2 * C_ * FF;
            int tile = j3 >> 9, l = (j3 >> 3) & 63, e = j3 & 7;
            int c_tile = tile >> 2, ks = tile & 3;
            int c = c_tile * 16 + (l & 15);
            int k = ks * 32 + (l >> 4) * 8 + e;
            wof[j3] = f2bf(Wo[k * C_ + c]);
        }
    }
    if (blockIdx.x == 0) {      // build cnt[24][32] once
        __shared__ int scnt[T_ * 32];
        for (int j = threadIdx.x; j < T_ * 32; j += 256) scnt[j] = 0;
        __syncthreads();
        for (int j = threadIdx.x; j < T_ * S_; j += 256) {
            int t = j / S_;
            atomicAdd(&scnt[t * 32 + idxs[j]], 1);
        }
        __syncthreads();
        for (int j = threadIdx.x; j < 192; j += 256) {
            unsigned v = (unsigned)scnt[4 * j] | ((unsigned)scnt[4 * j + 1] << 8)
                       | ((unsigned)scnt[4 * j + 2] << 16) | ((unsigned)scnt[4 * j + 3] << 24);
            ((unsigned*)cntg)[j] = v;
        }
    }
}

// ---------------- kernel 1: QKV projection via MFMA (x = query+tepe fused in staging)
__global__ __launch_bounds__(256) void k_qkv_mfma(
    const float* __restrict__ query, const float* __restrict__ tepe,
    const short* __restrict__ wqkvf,
    short* __restrict__ Q, short* __restrict__ K, short* __restrict__ V) {
    __shared__ __align__(16) short xs[BM * C_];
    int tid = threadIdx.x;
    int r0 = blockIdx.x * BM;
    {
        int row = tid >> 3;                 // 0..31
        int cb = (tid & 7) * 16;
        int gr = r0 + row;
        int t = gr % T_;
        int b = gr / (N_ * T_);
        const float* qsrc = query + (size_t)gr * C_ + cb;
        const float* tsrc = tepe + (size_t)(b * T_ + t) * C_ + cb;
        int swz0 = (row & 7) << 3;
#pragma unroll
        for (int i = 0; i < 4; i++) {
            float4 q4 = *(const float4*)(qsrc + 4 * i);
            float4 t4 = *(const float4*)(tsrc + 4 * i);
            short4_ sv;
            sv.x = f2bf(q4.x + t4.x); sv.y = f2bf(q4.y + t4.y);
            sv.z = f2bf(q4.z + t4.z); sv.w = f2bf(q4.w + t4.w);
            *(short4_*)&xs[(row * C_ + cb + 4 * i) ^ swz0] = sv;
        }
    }
    __syncthreads();
    int w = tid >> 6, l = tid & 63;
    int lr = l & 15, lk = l >> 4;
    int swz = (lr & 7) << 3;                // row-tile-invariant swizzle
    short8 bx[2][4];
#pragma unroll
    for (int rt = 0; rt < 2; rt++)
#pragma unroll
        for (int ks = 0; ks < 4; ks++)
            bx[rt][ks] = *(const short8*)&xs[((rt * 16 + lr) * C_ + ks * 32 + lk * 8) ^ swz];
    size_t base[2];
#pragma unroll
    for (int rt = 0; rt < 2; rt++) {
        int gr = r0 + rt * 16 + lr;
        int t = gr % T_;
        int n = (gr / T_) % N_;
        int b = gr / (N_ * T_);
        base[rt] = ((size_t)b * H_ * N_ + n) * (T_ * D_) + t * D_;
    }
#pragma unroll
    for (int jt = 0; jt < 6; jt++) {
        int ctile = w * 6 + jt;                 // c-tile index 0..23
        const short* ap = wqkvf + (size_t)ctile * 2048 + l * 8;
        short8 acur[4];
#pragma unroll
        for (int ks = 0; ks < 4; ks++) acur[ks] = *(const short8*)(ap + ks * 512);
        f32x4 acc[2] = {{0.f, 0.f, 0.f, 0.f}, {0.f, 0.f, 0.f, 0.f}};
#pragma unroll
        for (int ks = 0; ks < 4; ks++) {
#pragma unroll
            for (int rt = 0; rt < 2; rt++)
                acc[rt] = __builtin_amdgcn_mfma_f32_16x16x32_bf16(acur[ks], bx[rt][ks], acc[rt], 0, 0, 0);
        }
        int c0 = ctile * 16 + lk * 4;
        int m = c0 >> 7;
        int c = c0 & (C_ - 1);
        int h = c >> 4, d = c & 15;
        short* dst = (m == 0) ? Q : (m == 1) ? K : V;
#pragma unroll
        for (int rt = 0; rt < 2; rt++) {
            short4_ sv;
            sv.x = f2bf(acc[rt][0]); sv.y = f2bf(acc[rt][1]);
            sv.z = f2bf(acc[rt][2]); sv.w = f2bf(acc[rt][3]);
            *(short4_*)&dst[base[rt] + (size_t)h * (N_ * T_ * D_) + d] = sv;
        }
    }
}

// ---------------- kernel 2: attention, 4 INDEPENDENT units per block, ZERO barriers.
__global__ __launch_bounds__(256) void k_attn(
    const short* __restrict__ Q, const short* __restrict__ K, const short* __restrict__ V,
    const unsigned char* __restrict__ cntg, short* __restrict__ ctx) {
    __shared__ __align__(16) short Qbf[4][32 * 24], Kbf[4][32 * 24];
    __shared__ __align__(16) short Vt[4][16 * 40];       // [d][t2], cols 24-31 zeroed
    __shared__ __align__(16) short Pbf[4][32 * 40];      // attn weights, cols 24-31 zeroed
    __shared__ unsigned char cntS[T_ * 32];              // identical writes by all waves
    __shared__ float Mv[4][T_];
    __shared__ int keepS[4][T_];
    __shared__ float meanVs[4][D_];
    int tid = threadIdx.x;
    int wid = tid >> 6, l = tid & 63;
    int e = blockIdx.x * 4 + wid;
    const short* qb = Q + (size_t)e * (T_ * D_);
    const short* kb = K + (size_t)e * (T_ * D_);
    const short* vb = V + (size_t)e * (T_ * D_);
    if (l < 48) {
        int t = l >> 1, hf = l & 1;
        *(short8*)&Qbf[wid][t * 24 + hf * 8] = *(const short8*)(qb + t * 16 + hf * 8);
        *(short8*)&Kbf[wid][t * 24 + hf * 8] = *(const short8*)(kb + t * 16 + hf * 8);
    }
    for (int i = l; i < 96; i += 64) {
        int t = i >> 2, c4 = i & 3;
        short4_ v = *(const short4_*)(vb + t * 16 + c4 * 4);
        Vt[wid][(c4 * 4 + 0) * 40 + t] = v.x;
        Vt[wid][(c4 * 4 + 1) * 40 + t] = v.y;
        Vt[wid][(c4 * 4 + 2) * 40 + t] = v.z;
        Vt[wid][(c4 * 4 + 3) * 40 + t] = v.w;
    }
    for (int i = l; i < 128; i += 64) {       // zero Vt cols 24-31
        int d = i >> 3, c = 24 + (i & 7);
        Vt[wid][d * 40 + c] = 0;
    }
    for (int i = l; i < 192; i += 64)         // every wave writes the whole table
        ((int*)cntS)[i] = ((const int*)cntg)[i];
    if (l >= 48) {
        int d = l - 48;
        float s = 0.f;
        for (int t = 0; t < T_; t++) s += bf2f(Vt[wid][d * 40 + t]);
        meanVs[wid][d] = s * (1.0f / T_);
    }
    int lr = l & 15, lk = l >> 4;
    short8 zz = {};
    short8 kf0 = zz, kf1 = zz, qf0 = zz, qf1 = zz;
    if (lk < 2) {
        kf0 = *(const short8*)&Kbf[wid][lr * 24 + lk * 8];
        kf1 = *(const short8*)&Kbf[wid][(16 + lr) * 24 + lk * 8];
        qf0 = *(const short8*)&Qbf[wid][lr * 24 + lk * 8];
        qf1 = *(const short8*)&Qbf[wid][(16 + lr) * 24 + lk * 8];
    }
    f32x4 zf = {0.f, 0.f, 0.f, 0.f};
    f32x4 s00 = __builtin_amdgcn_mfma_f32_16x16x32_bf16(kf0, qf0, zf, 0, 0, 0);
    f32x4 s01 = __builtin_amdgcn_mfma_f32_16x16x32_bf16(kf1, qf0, zf, 0, 0, 0);
    f32x4 s10 = __builtin_amdgcn_mfma_f32_16x16x32_bf16(kf0, qf1, zf, 0, 0, 0);
    f32x4 s11 = __builtin_amdgcn_mfma_f32_16x16x32_bf16(kf1, qf1, zf, 0, 0, 0);
#pragma unroll
    for (int rt = 0; rt < 2; rt++) {
        int t = rt * 16 + lr;
        int tt = (t < T_) ? t : 0;
        f32x4 c0 = rt ? s10 : s00;
        f32x4 c1 = rt ? s11 : s01;
        float mx = -1e30f, sm = 0.f;
#pragma unroll
        for (int i = 0; i < 4; i++) {
            int cA = cntS[tt * 32 + lk * 4 + i];
            if (cA) { mx = fmaxf(mx, c0[i]); sm += (float)cA * c0[i]; }
        }
        if (lk < 2) {
#pragma unroll
            for (int i = 0; i < 4; i++) {
                int cB = cntS[tt * 32 + 16 + lk * 4 + i];
                if (cB) { mx = fmaxf(mx, c1[i]); sm += (float)cB * c1[i]; }
            }
        }
        mx = fmaxf(mx, __shfl_xor(mx, 16));
        mx = fmaxf(mx, __shfl_xor(mx, 32));
        sm += __shfl_xor(sm, 16);
        sm += __shfl_xor(sm, 32);
        if (lk == 0 && t < T_) Mv[wid][t] = mx - sm * (1.0f / S_);
    }
    if (l < T_) {
        float mt = Mv[wid][l];
        int cnt2 = 0;
        for (int t2 = 0; t2 < T_; t2++) {
            float m2 = Mv[wid][t2];
            cnt2 += (m2 > mt) || (m2 == mt && t2 < l);
        }
        keepS[wid][l] = (cnt2 < U_) ? 1 : 0;
    }
#pragma unroll
    for (int rt = 0; rt < 2; rt++) {
        f32x4 c0 = rt ? s10 : s00;
        f32x4 c1 = rt ? s11 : s01;
        float lm = fmaxf(fmaxf(c0[0], c0[1]), fmaxf(c0[2], c0[3]));
        if (lk < 2) lm = fmaxf(lm, fmaxf(fmaxf(c1[0], c1[1]), fmaxf(c1[2], c1[3])));
        lm = fmaxf(lm, __shfl_xor(lm, 16));
        lm = fmaxf(lm, __shfl_xor(lm, 32));
        float e0[4], e1[4];
        float ls = 0.f;
#pragma unroll
        for (int i = 0; i < 4; i++) { e0[i] = __expf(0.25f * (c0[i] - lm)); ls += e0[i]; }
#pragma unroll
        for (int i = 0; i < 4; i++) { e1[i] = (lk < 2) ? __expf(0.25f * (c1[i] - lm)) : 0.f; ls += e1[i]; }
        ls += __shfl_xor(ls, 16);
        ls += __shfl_xor(ls, 32);
        float inv = 1.0f / ls;
        short4_ w0, w1;
        w0.x = f2bf(e0[0] * inv); w0.y = f2bf(e0[1] * inv);
        w0.z = f2bf(e0[2] * inv); w0.w = f2bf(e0[3] * inv);
        w1.x = f2bf(e1[0] * inv); w1.y = f2bf(e1[1] * inv);
        w1.z = f2bf(e1[2] * inv); w1.w = f2bf(e1[3] * inv);
        int trow = rt * 16 + lr;
        *(short4_*)&Pbf[wid][trow * 40 + lk * 4] = w0;
        *(short4_*)&Pbf[wid][trow * 40 + 16 + lk * 4] = w1;   // lk>=2 writes zeros
    }
    short8 vf = *(const short8*)&Vt[wid][lr * 40 + lk * 8];
    short8 pf0 = *(const short8*)&Pbf[wid][lr * 40 + lk * 8];
    short8 pf1 = *(const short8*)&Pbf[wid][(16 + lr) * 40 + lk * 8];
    f32x4 u0 = __builtin_amdgcn_mfma_f32_16x16x32_bf16(vf, pf0, zf, 0, 0, 0);
    f32x4 u1 = __builtin_amdgcn_mfma_f32_16x16x32_bf16(vf, pf1, zf, 0, 0, 0);
    int b = e / (H_ * N_);
    int h = (e / N_) % H_;
    int n = e % N_;
    float4 mv4 = *(const float4*)&meanVs[wid][lk * 4];
#pragma unroll
    for (int rt = 0; rt < 2; rt++) {
        int t = rt * 16 + lr;
        if (t < T_) {
            f32x4 u = rt ? u1 : u0;
            float4 o;
            if (keepS[wid][t]) { o.x = u[0]; o.y = u[1]; o.z = u[2]; o.w = u[3]; }
            else o = mv4;
            short4_ sv;
            sv.x = f2bf(o.x); sv.y = f2bf(o.y); sv.z = f2bf(o.z); sv.w = f2bf(o.w);
            *(short4_*)&ctx[((size_t)(b * N_ + n) * T_ + t) * C_ + h * D_ + lk * 4] = sv;
        }
    }
}

// ---------------- kernel 3: fused tail, 64 rows / 256 threads / 48 KB -> 3 blocks/CU.
// Register front-end (round-15): ctx->regs, row-partitioned Wo, LN1 in registers.
// Two-pass FF (round-14): hbf 32 KB. yf OVERLAPS x1bf's first 1 KB -> MUST barrier
// between residual reads and yf writes (round-18 NaN post-mortem). launch_bounds
// min-waves MUST stay 4: 6 caps VGPR at 85 -> 40-VGPR spill collapse (r11/r13).
__global__ __launch_bounds__(256, 4) void k_tail(
    const short* __restrict__ ctx, const short* __restrict__ wof, const float* __restrict__ bo,
    const float* __restrict__ query, const float* __restrict__ tepe,
    const float* __restrict__ g1, const float* __restrict__ b1,
    const short* __restrict__ w1f, const float* __restrict__ b1f,
    const short* __restrict__ w2f, const float* __restrict__ b2f,
    const float* __restrict__ g2, const float* __restrict__ b2ln,
    float* __restrict__ out) {
    __shared__ __align__(16) char smem[49152];
    short* hbf = (short*)smem;                    // [64][256] bf16 swizzled (per pass)
    float (*yf)[132] = (float(*)[132])smem;       // f32 y (33.8 KB), after res-drain BAR
    short* x1bf = (short*)(smem + 32768);         // [64][128] bf16 swizzled
    int tid = threadIdx.x;
    int r0 = blockIdx.x * BMT;
    int w = tid >> 6, l = tid & 63;
    int lr = l & 15, lk = l >> 4;
    int swz = (lr & 7) << 3;
    int myloc = w * 16 + lr;                      // this lane's row, 0..63
    int gr = r0 + myloc;
    int t = gr % T_;
    int b = gr / (N_ * T_);
    // ---- P0: direct-to-register loads (no LDS, no barrier)
    const short* csrc = ctx + (size_t)gr * C_;
    short8 bc[4];
#pragma unroll
    for (int ks = 0; ks < 4; ks++)
        bc[ks] = *(const short8*)(csrc + ks * 32 + lk * 8);
    const float* qsrc = query + (size_t)gr * C_;
    const float* tsrc = tepe + (size_t)(b * T_ + t) * C_;
    float4 xres[8];
#pragma unroll
    for (int ct = 0; ct < 8; ct++) {
        float4 q4 = *(const float4*)(qsrc + ct * 16 + lk * 4);
        float4 t4 = *(const float4*)(tsrc + ct * 16 + lk * 4);
        xres[ct].x = q4.x + t4.x; xres[ct].y = q4.y + t4.y;
        xres[ct].z = q4.z + t4.z; xres[ct].w = q4.w + t4.w;
    }
    // ---- P1: Wo GEMM, row-partitioned (wave reads ALL wof; output in D-layout regs)
#pragma unroll
    for (int ct = 0; ct < 8; ct++) {
        f32x4 acc = {0.f, 0.f, 0.f, 0.f};
#pragma unroll
        for (int ks = 0; ks < 4; ks++) {
            short8 aw = *(const short8*)(wof + (size_t)(ct * 4 + ks) * 512 + l * 8);
            acc = __builtin_amdgcn_mfma_f32_16x16x32_bf16(aw, bc[ks], acc, 0, 0, 0);
        }
        float4 bo4 = *(const float4*)(bo + ct * 16 + lk * 4);
        xres[ct].x += acc[0] + bo4.x;
        xres[ct].y += acc[1] + bo4.y;
        xres[ct].z += acc[2] + bo4.z;
        xres[ct].w += acc[3] + bo4.w;
    }
    // ---- P2: LN1 fully in registers (lanes {l, l^16, l^32} share row myloc)
    {
        float s = 0.f;
#pragma unroll
        for (int ct = 0; ct < 8; ct++)
            s += xres[ct].x + xres[ct].y + xres[ct].z + xres[ct].w;
        s += __shfl_xor(s, 16);
        s += __shfl_xor(s, 32);
        float mean = s * (1.f / C_);
        float vv = 0.f;
#pragma unroll
        for (int ct = 0; ct < 8; ct++) {
            float dx = xres[ct].x - mean, dy = xres[ct].y - mean;
            float dz = xres[ct].z - mean, dw = xres[ct].w - mean;
            vv += dx * dx + dy * dy + dz * dz + dw * dw;
        }
        vv += __shfl_xor(vv, 16);
        vv += __shfl_xor(vv, 32);
        float rstd = rsqrtf(vv * (1.f / C_) + 1e-5f);
#pragma unroll
        for (int ct = 0; ct < 8; ct++) {
            float4 gv = *(const float4*)(g1 + ct * 16 + lk * 4);
            float4 bv = *(const float4*)(b1 + ct * 16 + lk * 4);
            short4_ xv;
            xv.x = f2bf((xres[ct].x - mean) * rstd * gv.x + bv.x);
            xv.y = f2bf((xres[ct].y - mean) * rstd * gv.y + bv.y);
            xv.z = f2bf((xres[ct].z - mean) * rstd * gv.z + bv.z);
            xv.w = f2bf((xres[ct].w - mean) * rstd * gv.w + bv.w);
            *(short4_*)&x1bf[(myloc * C_ + ct * 16 + lk * 4) ^ swz] = xv;
        }
    }
    // prefetch pass0/jt0 weights (independent of x1bf; in flight across BAR1)
    short8 pre1[4];
    {
        const short* ap = w1f + (size_t)(w * 4) * 2048 + l * 8;
#pragma unroll
        for (int ks = 0; ks < 4; ks++) pre1[ks] = *(const short8*)(ap + ks * 512);
    }
    __syncthreads();                              // BAR1: x1bf ready
    // ---- FF in two K-half passes; acc2 persists in registers
    f32x4 acc2[2][4] = {{{0.f, 0.f, 0.f, 0.f}, {0.f, 0.f, 0.f, 0.f},
                         {0.f, 0.f, 0.f, 0.f}, {0.f, 0.f, 0.f, 0.f}},
                        {{0.f, 0.f, 0.f, 0.f}, {0.f, 0.f, 0.f, 0.f},
                         {0.f, 0.f, 0.f, 0.f}, {0.f, 0.f, 0.f, 0.f}}};
    for (int p = 0; p < 2; p++) {
        // G1 pass p: jtiles p*16 + w*4 + {0..3} -> hbf (local j in [0,256))
        for (int jt = 0; jt < 4; jt++) {
            int jtile = p * 16 + w * 4 + jt;
            short8 acur[4];
            if (p == 0 && jt == 0) {
#pragma unroll
                for (int ks = 0; ks < 4; ks++) acur[ks] = pre1[ks];
            } else {
                const short* ap = w1f + (size_t)jtile * 2048 + l * 8;
#pragma unroll
                for (int ks = 0; ks < 4; ks++) acur[ks] = *(const short8*)(ap + ks * 512);
            }
            f32x4 a1[4] = {{0.f, 0.f, 0.f, 0.f}, {0.f, 0.f, 0.f, 0.f},
                           {0.f, 0.f, 0.f, 0.f}, {0.f, 0.f, 0.f, 0.f}};
#pragma unroll
            for (int ks = 0; ks < 4; ks++) {
                short8 bx4[4];
#pragma unroll
                for (int rt = 0; rt < 4; rt++)
                    bx4[rt] = *(const short8*)&x1bf[((rt * 16 + lr) * C_ + ks * 32 + lk * 8) ^ swz];
#pragma unroll
                for (int rt = 0; rt < 4; rt++)
                    a1[rt] = __builtin_amdgcn_mfma_f32_16x16x32_bf16(acur[ks], bx4[rt], a1[rt], 0, 0, 0);
            }
            int j0g = jtile * 16 + lk * 4;
            int j0l = (w * 4 + jt) * 16 + lk * 4;
            float4 b1v = *(const float4*)(b1f + j0g);
#pragma unroll
            for (int rt = 0; rt < 4; rt++) {
                int rr = rt * 16 + lr;
                short4_ hv;
                hv.x = f2bf(fmaxf(a1[rt][0] + b1v.x, 0.f));
                hv.y = f2bf(fmaxf(a1[rt][1] + b1v.y, 0.f));
                hv.z = f2bf(fmaxf(a1[rt][2] + b1v.z, 0.f));
                hv.w = f2bf(fmaxf(a1[rt][3] + b1v.w, 0.f));
                *(short4_*)&hbf[(rr * 256 + j0l) ^ swz] = hv;
            }
        }
        __syncthreads();            // hbf ready
        // G2 pass p: local ks 0..7 (global K index p*8+ks); hx hoisted per ks
#pragma unroll 2
        for (int ks = 0; ks < 8; ks++) {
            short8 hx[4];
#pragma unroll
            for (int rt = 0; rt < 4; rt++)
                hx[rt] = *(const short8*)&hbf[((rt * 16 + lr) * 256 + ks * 32 + lk * 8) ^ swz];
#pragma unroll
            for (int ct = 0; ct < 2; ct++) {
                short8 aw = *(const short8*)(w2f + ((size_t)((w * 2 + ct) * 16 + p * 8 + ks)) * 512 + l * 8);
#pragma unroll
                for (int rt = 0; rt < 4; rt++)
                    acc2[ct][rt] = __builtin_amdgcn_mfma_f32_16x16x32_bf16(aw, hx[rt], acc2[ct][rt], 0, 0, 0);
            }
        }
        __syncthreads();            // hbf reads done -> next pass may overwrite
    }
    // ---- epilogue: residual + bias into regs (x1bf still intact)
    float4 res[2][4], b2v[2];
#pragma unroll
    for (int ct = 0; ct < 2; ct++) {
        int cc = (w * 2 + ct) * 16 + lk * 4;
        b2v[ct] = *(const float4*)(b2f + cc);
#pragma unroll
        for (int rt = 0; rt < 4; rt++) {
            short4_ rb = *(const short4_*)&x1bf[((rt * 16 + lr) * C_ + cc) ^ swz];
            res[ct][rt].x = bf2f(rb.x); res[ct][rt].y = bf2f(rb.y);
            res[ct][rt].z = bf2f(rb.z); res[ct][rt].w = bf2f(rb.w);
        }
    }
    __syncthreads();    // CRITICAL: drain ALL waves' x1bf reads before yf (which
                        // overlaps x1bf rows 0-3) is written — r18 NaN fix
#pragma unroll
    for (int ct = 0; ct < 2; ct++) {
        int cc = (w * 2 + ct) * 16 + lk * 4;
#pragma unroll
        for (int rt = 0; rt < 4; rt++) {
            int rr = rt * 16 + lr;
            float4 o;
            o.x = acc2[ct][rt][0] + b2v[ct].x + res[ct][rt].x;
            o.y = acc2[ct][rt][1] + b2v[ct].y + res[ct][rt].y;
            o.z = acc2[ct][rt][2] + b2v[ct].z + res[ct][rt].z;
            o.w = acc2[ct][rt][3] + b2v[ct].w + res[ct][rt].w;
            *(float4*)&yf[rr][cc] = o;
        }
    }
    __syncthreads();                         // yf ready
    // ---- LN2 + store (two 32-row halves)
#pragma unroll
    for (int half = 0; half < 2; half++) {
        int r = (tid >> 3) + half * 32;
        int q = tid & 7;
        int cb = q * 16;
        float vals[16];
        float s = 0.f;
#pragma unroll
        for (int i = 0; i < 16; i++) { vals[i] = yf[r][cb + i]; s += vals[i]; }
        s += __shfl_xor(s, 1, 8);
        s += __shfl_xor(s, 2, 8);
        s += __shfl_xor(s, 4, 8);
        float mean = s * (1.f / C_);
        float vv = 0.f;
#pragma unroll
        for (int i = 0; i < 16; i++) { float d = vals[i] - mean; vv += d * d; }
        vv += __shfl_xor(vv, 1, 8);
        vv += __shfl_xor(vv, 2, 8);
        vv += __shfl_xor(vv, 4, 8);
        float rstd = rsqrtf(vv * (1.f / C_) + 1e-5f);
        float* op = out + (size_t)(r0 + r) * C_ + cb;
#pragma unroll
        for (int i4 = 0; i4 < 4; i4++) {
            float4 gv = *(const float4*)(g2 + cb + 4 * i4);
            float4 bv = *(const float4*)(b2ln + cb + 4 * i4);
            float4 ov;
            ov.x = (vals[4 * i4 + 0] - mean) * rstd * gv.x + bv.x;
            ov.y = (vals[4 * i4 + 1] - mean) * rstd * gv.y + bv.y;
            ov.z = (vals[4 * i4 + 2] - mean) * rstd * gv.z + bv.z;
            ov.w = (vals[4 * i4 + 3] - mean) * rstd * gv.w + bv.w;
            *(float4*)(op + 4 * i4) = ov;
        }
    }
}

extern "C" void kernel_launch(void* const* d_in, const int* in_sizes, int n_in,
                              void* d_out, int out_size, void* d_ws, size_t ws_size,
                              hipStream_t stream) {
    const float* query = (const float*)d_in[2];
    const int* time_enc = (const int*)d_in[4];
    const int* index_sample = (const int*)d_in[5];
    const float* e_min = (const float*)d_in[6];
    const float* e_hr  = (const float*)d_in[7];
    const float* e_wd  = (const float*)d_in[8];
    const float* e_mo  = (const float*)d_in[9];
    const float* e_yr  = (const float*)d_in[10];
    const float* Wq = (const float*)d_in[11];
    const float* Wk = (const float*)d_in[12];
    const float* Wv = (const float*)d_in[13];
    const float* Wo = (const float*)d_in[14];
    const float* bo = (const float*)d_in[15];
    const float* ffw1 = (const float*)d_in[16];
    const float* ffb1 = (const float*)d_in[17];
    const float* ffw2 = (const float*)d_in[18];
    const float* ffb2 = (const float*)d_in[19];
    const float* ln1g = (const float*)d_in[20];
    const float* ln1b = (const float*)d_in[21];
    const float* ln2g = (const float*)d_in[22];
    const float* ln2b = (const float*)d_in[23];

    float* ws = (float*)d_ws;
    float* tepe = ws;                     // TEPE_N floats
    float* region1 = ws + TEPE_N;         // NX floats: bf16 Q
    float* region2 = region1 + NX;        // NX floats: bf16 K (first half) + w1f/w2f/wof (second half)
    float* region3 = region2 + NX;        // NX floats: bf16 V
    float* region4 = region3 + NX;        // NX floats: bf16 ctx + wqkvf + cntg

    short* Qb = (short*)region1;
    short* Kb = (short*)region2;
    short* Vb = (short*)region3;
    short* ctxb = (short*)region4;
    short* wqkvf = (short*)region4 + NX;        // dead after qkv
    unsigned char* cntg = (unsigned char*)((short*)region4 + NX + 49152);  // 768 B
    short* w1f = (short*)region2 + NX;          // second half of region2 (K uses first)
    short* w2f = w1f + C_ * FF;
    short* wof = w2f + C_ * FF;

    k_prep<<<dim3(PREP_N / 256), dim3(256), 0, stream>>>(
        time_enc, e_min, e_hr, e_wd, e_mo, e_yr, tepe, index_sample, cntg,
        Wq, Wk, Wv, wqkvf, ffw1, ffw2, Wo, w1f, w2f, wof);
    k_qkv_mfma<<<dim3(NBLK_MM), dim3(256), 0, stream>>>(
        query, tepe, wqkvf, Qb, Kb, Vb);
    k_attn<<<dim3(NUNIT / 4), dim3(256), 0, stream>>>(
        Qb, Kb, Vb, cntg, ctxb);
    k_tail<<<dim3(NBLK_T), dim3(256), 0, stream>>>(
        ctxb, wof, bo, query, tepe, ln1g, ln1b,
        w1f, ffb1, w2f, ffb2, ln2g, ln2b, (float*)d_out);
}

// Round 20
// 169.085 us; speedup vs baseline: 1.0986x; 1.0986x over previous
//
#include <hip/hip_runtime.h>
#include <hip/hip_bf16.h>
#include <cmath>

namespace {
constexpr int B_ = 16, N_ = 307, T_ = 24, C_ = 128, H_ = 8, D_ = 16, S_ = 20, U_ = 20;
constexpr int NROW = B_ * N_ * T_;          // 117888
constexpr int NX = NROW * C_;               // 15089664
constexpr int TEPE_N = B_ * T_ * C_;        // 49152
constexpr int FF = 4 * C_;                  // 512
constexpr int BM = 32;                      // rows per qkv block
constexpr int NBLK_MM = NROW / BM;          // 3684
constexpr int BMT = 32;                     // rows per tail block (256 thr, 4 waves)
constexpr int NBLK_T = NROW / BMT;          // 3684
constexpr int NUNIT = B_ * H_ * N_;         // 39296
}

typedef __attribute__((ext_vector_type(8))) short short8;
typedef __attribute__((ext_vector_type(4))) short short4_;
typedef __attribute__((ext_vector_type(4))) float f32x4;

__device__ inline short f2bf(float v) {
    union { float f; unsigned u; } a; a.f = v;
    unsigned r = a.u + 0x7fff + ((a.u >> 16) & 1);   // round-to-nearest-even
    return (short)(r >> 16);
}
__device__ inline float bf2f(short s) {
    return __bfloat162float(*(const __hip_bfloat16*)&s);
}

// ---------------- kernel 0: tepe + (block 0) global sample-count table
__global__ void k_tepe(const int* __restrict__ te,
                       const float* __restrict__ e_min, const float* __restrict__ e_hr,
                       const float* __restrict__ e_wd, const float* __restrict__ e_mo,
                       const float* __restrict__ e_yr, float* __restrict__ tepe,
                       const int* __restrict__ idxs, unsigned char* __restrict__ cntg) {
    int i = blockIdx.x * blockDim.x + threadIdx.x;
    if (i < TEPE_N) {
        int c = i & (C_ - 1);
        int bt = i >> 7;              // b*T + t
        int t = bt % T_;
        const int* enc = te + bt * 5;
        float v = e_min[enc[0] * C_ + c] + e_hr[enc[1] * C_ + c] + e_wd[enc[2] * C_ + c]
                + e_mo[enc[3] * C_ + c] + e_yr[enc[4] * C_ + c];
        float ang = (float)t * expf(-(float)(c & ~1) * (9.210340371976184f / 128.0f));
        v += (c & 1) ? cosf(ang) : sinf(ang);
        tepe[i] = v;
    }
    if (blockIdx.x == 0) {      // build cnt[24][32] once (shared by all attn blocks)
        __shared__ int scnt[T_ * 32];
        for (int j = threadIdx.x; j < T_ * 32; j += 256) scnt[j] = 0;
        __syncthreads();
        for (int j = threadIdx.x; j < T_ * S_; j += 256) {
            int t = j / S_;
            atomicAdd(&scnt[t * 32 + idxs[j]], 1);
        }
        __syncthreads();
        for (int j = threadIdx.x; j < 192; j += 256) {
            unsigned v = (unsigned)scnt[4 * j] | ((unsigned)scnt[4 * j + 1] << 8)
                       | ((unsigned)scnt[4 * j + 2] << 16) | ((unsigned)scnt[4 * j + 3] << 24);
            ((unsigned*)cntg)[j] = v;
        }
    }
}

// ---------------- weight converts: FRAGMENT-LINEAR layout (round 4).
__global__ void k_wcvt_qkv(const float* __restrict__ Wq, const float* __restrict__ Wk,
                           const float* __restrict__ Wv, short* __restrict__ wqkvf) {
    int i = blockIdx.x * 256 + threadIdx.x;     // 49152
    int tile = i >> 9, l = (i >> 3) & 63, e = i & 7;
    int c_tile = tile >> 2, ks = tile & 3;
    int c_all = c_tile * 16 + (l & 15);
    int k = ks * 32 + (l >> 4) * 8 + e;
    int m = c_all >> 7, c = c_all & (C_ - 1);
    const float* W = (m == 0) ? Wq : (m == 1) ? Wk : Wv;
    wqkvf[i] = f2bf(W[k * C_ + c]);
}

__global__ void k_wcvt2(const float* __restrict__ w1, const float* __restrict__ w2,
                        const float* __restrict__ Wo,
                        short* __restrict__ w1f, short* __restrict__ w2f,
                        short* __restrict__ wof) {
    int i = blockIdx.x * 256 + threadIdx.x;     // 147456
    if (i < C_ * FF) {
        int tile = i >> 9, l = (i >> 3) & 63, e = i & 7;
        int jtile = tile >> 2, ks = tile & 3;
        int j = jtile * 16 + (l & 15);
        int k = ks * 32 + (l >> 4) * 8 + e;
        w1f[i] = f2bf(w1[k * FF + j]);          // w1 is [C][FF] = [k][j]
    } else if (i < 2 * C_ * FF) {
        int i2 = i - C_ * FF;
        int tile = i2 >> 9, l = (i2 >> 3) & 63, e = i2 & 7;
        int c_tile = tile >> 4, ks = tile & 15;
        int c = c_tile * 16 + (l & 15);
        int j = ks * 32 + (l >> 4) * 8 + e;
        w2f[i2] = f2bf(w2[j * C_ + c]);         // w2 is [FF][C] = [j][c]
    } else {
        int i3 = i - 2 * C_ * FF;
        int tile = i3 >> 9, l = (i3 >> 3) & 63, e = i3 & 7;
        int c_tile = tile >> 2, ks = tile & 3;
        int c = c_tile * 16 + (l & 15);
        int k = ks * 32 + (l >> 4) * 8 + e;
        wof[i3] = f2bf(Wo[k * C_ + c]);         // Wo is [C][C] = [k][c]
    }
}

// ---------------- kernel 1: QKV projection via MFMA (x = query+tepe fused in staging)
__global__ __launch_bounds__(256) void k_qkv_mfma(
    const float* __restrict__ query, const float* __restrict__ tepe,
    const short* __restrict__ wqkvf,
    short* __restrict__ Q, short* __restrict__ K, short* __restrict__ V) {
    __shared__ __align__(16) short xs[BM * C_];
    int tid = threadIdx.x;
    int r0 = blockIdx.x * BM;
    {
        int row = tid >> 3;                 // 0..31
        int cb = (tid & 7) * 16;
        int gr = r0 + row;
        int t = gr % T_;
        int b = gr / (N_ * T_);
        const float* qsrc = query + (size_t)gr * C_ + cb;
        const float* tsrc = tepe + (size_t)(b * T_ + t) * C_ + cb;
        int swz0 = (row & 7) << 3;
#pragma unroll
        for (int i = 0; i < 4; i++) {
            float4 q4 = *(const float4*)(qsrc + 4 * i);
            float4 t4 = *(const float4*)(tsrc + 4 * i);
            short4_ sv;
            sv.x = f2bf(q4.x + t4.x); sv.y = f2bf(q4.y + t4.y);
            sv.z = f2bf(q4.z + t4.z); sv.w = f2bf(q4.w + t4.w);
            *(short4_*)&xs[(row * C_ + cb + 4 * i) ^ swz0] = sv;
        }
    }
    __syncthreads();
    int w = tid >> 6, l = tid & 63;
    int lr = l & 15, lk = l >> 4;
    int swz = (lr & 7) << 3;                // row-tile-invariant swizzle
    short8 bx[2][4];
#pragma unroll
    for (int rt = 0; rt < 2; rt++)
#pragma unroll
        for (int ks = 0; ks < 4; ks++)
            bx[rt][ks] = *(const short8*)&xs[((rt * 16 + lr) * C_ + ks * 32 + lk * 8) ^ swz];
    size_t base[2];
#pragma unroll
    for (int rt = 0; rt < 2; rt++) {
        int gr = r0 + rt * 16 + lr;
        int t = gr % T_;
        int n = (gr / T_) % N_;
        int b = gr / (N_ * T_);
        base[rt] = ((size_t)b * H_ * N_ + n) * (T_ * D_) + t * D_;
    }
#pragma unroll
    for (int jt = 0; jt < 6; jt++) {
        int ctile = w * 6 + jt;                 // c-tile index 0..23
        const short* ap = wqkvf + (size_t)ctile * 2048 + l * 8;
        short8 acur[4];
#pragma unroll
        for (int ks = 0; ks < 4; ks++) acur[ks] = *(const short8*)(ap + ks * 512);
        f32x4 acc[2] = {{0.f, 0.f, 0.f, 0.f}, {0.f, 0.f, 0.f, 0.f}};
#pragma unroll
        for (int ks = 0; ks < 4; ks++) {
#pragma unroll
            for (int rt = 0; rt < 2; rt++)
                acc[rt] = __builtin_amdgcn_mfma_f32_16x16x32_bf16(acur[ks], bx[rt][ks], acc[rt], 0, 0, 0);
        }
        int c0 = ctile * 16 + lk * 4;
        int m = c0 >> 7;
        int c = c0 & (C_ - 1);
        int h = c >> 4, d = c & 15;
        short* dst = (m == 0) ? Q : (m == 1) ? K : V;
#pragma unroll
        for (int rt = 0; rt < 2; rt++) {
            short4_ sv;
            sv.x = f2bf(acc[rt][0]); sv.y = f2bf(acc[rt][1]);
            sv.z = f2bf(acc[rt][2]); sv.w = f2bf(acc[rt][3]);
            *(short4_*)&dst[base[rt] + (size_t)h * (N_ * T_ * D_) + d] = sv;
        }
    }
}

// ---------------- kernel 2: attention, 4 units per 256-thread block (1 wave/unit)
__global__ __launch_bounds__(256) void k_attn(
    const short* __restrict__ Q, const short* __restrict__ K, const short* __restrict__ V,
    const unsigned char* __restrict__ cntg, short* __restrict__ ctx) {
    __shared__ __align__(16) short Qbf[4][32 * 24], Kbf[4][32 * 24];
    __shared__ __align__(16) short Vt[4][16 * 40];       // [d][t2], cols 24-31 zeroed
    __shared__ __align__(16) short Pbf[4][32 * 40];      // attn weights, cols 24-31 zeroed
    __shared__ unsigned char cntS[T_ * 32];              // shared by all 4 units
    __shared__ float Mv[4][T_];
    __shared__ int keepS[4][T_];
    __shared__ float meanVs[4][D_];
    int tid = threadIdx.x;
    int wid = tid >> 6, l = tid & 63;
    int e = blockIdx.x * 4 + wid;
    const short* qb = Q + (size_t)e * (T_ * D_);
    const short* kb = K + (size_t)e * (T_ * D_);
    const short* vb = V + (size_t)e * (T_ * D_);
    if (l < 48) {
        int t = l >> 1, hf = l & 1;
        *(short8*)&Qbf[wid][t * 24 + hf * 8] = *(const short8*)(qb + t * 16 + hf * 8);
        *(short8*)&Kbf[wid][t * 24 + hf * 8] = *(const short8*)(kb + t * 16 + hf * 8);
    }
    for (int i = l; i < 96; i += 64) {
        int t = i >> 2, c4 = i & 3;
        short4_ v = *(const short4_*)(vb + t * 16 + c4 * 4);
        Vt[wid][(c4 * 4 + 0) * 40 + t] = v.x;
        Vt[wid][(c4 * 4 + 1) * 40 + t] = v.y;
        Vt[wid][(c4 * 4 + 2) * 40 + t] = v.z;
        Vt[wid][(c4 * 4 + 3) * 40 + t] = v.w;
    }
    for (int i = l; i < 128; i += 64) {       // zero Vt cols 24-31
        int d = i >> 3, c = 24 + (i & 7);
        Vt[wid][d * 40 + c] = 0;
    }
    if (tid < 192) ((int*)cntS)[tid] = ((const int*)cntg)[tid];
    __syncthreads();
    if (l >= 48) {
        int d = l - 48;
        float s = 0.f;
        for (int t = 0; t < T_; t++) s += bf2f(Vt[wid][d * 40 + t]);
        meanVs[wid][d] = s * (1.0f / T_);
    }
    int lr = l & 15, lk = l >> 4;
    short8 zz = {};
    short8 kf0 = zz, kf1 = zz, qf0 = zz, qf1 = zz;
    if (lk < 2) {
        kf0 = *(const short8*)&Kbf[wid][lr * 24 + lk * 8];
        kf1 = *(const short8*)&Kbf[wid][(16 + lr) * 24 + lk * 8];
        qf0 = *(const short8*)&Qbf[wid][lr * 24 + lk * 8];
        qf1 = *(const short8*)&Qbf[wid][(16 + lr) * 24 + lk * 8];
    }
    f32x4 zf = {0.f, 0.f, 0.f, 0.f};
    f32x4 s00 = __builtin_amdgcn_mfma_f32_16x16x32_bf16(kf0, qf0, zf, 0, 0, 0);
    f32x4 s01 = __builtin_amdgcn_mfma_f32_16x16x32_bf16(kf1, qf0, zf, 0, 0, 0);
    f32x4 s10 = __builtin_amdgcn_mfma_f32_16x16x32_bf16(kf0, qf1, zf, 0, 0, 0);
    f32x4 s11 = __builtin_amdgcn_mfma_f32_16x16x32_bf16(kf1, qf1, zf, 0, 0, 0);
#pragma unroll
    for (int rt = 0; rt < 2; rt++) {
        int t = rt * 16 + lr;
        int tt = (t < T_) ? t : 0;
        f32x4 c0 = rt ? s10 : s00;
        f32x4 c1 = rt ? s11 : s01;
        float mx = -1e30f, sm = 0.f;
#pragma unroll
        for (int i = 0; i < 4; i++) {
            int cA = cntS[tt * 32 + lk * 4 + i];
            if (cA) { mx = fmaxf(mx, c0[i]); sm += (float)cA * c0[i]; }
        }
        if (lk < 2) {
#pragma unroll
            for (int i = 0; i < 4; i++) {
                int cB = cntS[tt * 32 + 16 + lk * 4 + i];
                if (cB) { mx = fmaxf(mx, c1[i]); sm += (float)cB * c1[i]; }
            }
        }
        mx = fmaxf(mx, __shfl_xor(mx, 16));
        mx = fmaxf(mx, __shfl_xor(mx, 32));
        sm += __shfl_xor(sm, 16);
        sm += __shfl_xor(sm, 32);
        if (lk == 0 && t < T_) Mv[wid][t] = mx - sm * (1.0f / S_);
    }
    __syncthreads();
    if (l < T_) {
        float mt = Mv[wid][l];
        int cnt2 = 0;
        for (int t2 = 0; t2 < T_; t2++) {
            float m2 = Mv[wid][t2];
            cnt2 += (m2 > mt) || (m2 == mt && t2 < l);
        }
        keepS[wid][l] = (cnt2 < U_) ? 1 : 0;
    }
#pragma unroll
    for (int rt = 0; rt < 2; rt++) {
        f32x4 c0 = rt ? s10 : s00;
        f32x4 c1 = rt ? s11 : s01;
        float lm = fmaxf(fmaxf(c0[0], c0[1]), fmaxf(c0[2], c0[3]));
        if (lk < 2) lm = fmaxf(lm, fmaxf(fmaxf(c1[0], c1[1]), fmaxf(c1[2], c1[3])));
        lm = fmaxf(lm, __shfl_xor(lm, 16));
        lm = fmaxf(lm, __shfl_xor(lm, 32));
        float e0[4], e1[4];
        float ls = 0.f;
#pragma unroll
        for (int i = 0; i < 4; i++) { e0[i] = __expf(0.25f * (c0[i] - lm)); ls += e0[i]; }
#pragma unroll
        for (int i = 0; i < 4; i++) { e1[i] = (lk < 2) ? __expf(0.25f * (c1[i] - lm)) : 0.f; ls += e1[i]; }
        ls += __shfl_xor(ls, 16);
        ls += __shfl_xor(ls, 32);
        float inv = 1.0f / ls;
        short4_ w0, w1;
        w0.x = f2bf(e0[0] * inv); w0.y = f2bf(e0[1] * inv);
        w0.z = f2bf(e0[2] * inv); w0.w = f2bf(e0[3] * inv);
        w1.x = f2bf(e1[0] * inv); w1.y = f2bf(e1[1] * inv);
        w1.z = f2bf(e1[2] * inv); w1.w = f2bf(e1[3] * inv);
        int trow = rt * 16 + lr;
        *(short4_*)&Pbf[wid][trow * 40 + lk * 4] = w0;
        *(short4_*)&Pbf[wid][trow * 40 + 16 + lk * 4] = w1;   // lk>=2 writes zeros
    }
    __syncthreads();
    short8 vf = *(const short8*)&Vt[wid][lr * 40 + lk * 8];
    short8 pf0 = *(const short8*)&Pbf[wid][lr * 40 + lk * 8];
    short8 pf1 = *(const short8*)&Pbf[wid][(16 + lr) * 40 + lk * 8];
    f32x4 u0 = __builtin_amdgcn_mfma_f32_16x16x32_bf16(vf, pf0, zf, 0, 0, 0);
    f32x4 u1 = __builtin_amdgcn_mfma_f32_16x16x32_bf16(vf, pf1, zf, 0, 0, 0);
    int b = e / (H_ * N_);
    int h = (e / N_) % H_;
    int n = e % N_;
    float4 mv4 = *(const float4*)&meanVs[wid][lk * 4];
#pragma unroll
    for (int rt = 0; rt < 2; rt++) {
        int t = rt * 16 + lr;
        if (t < T_) {
            f32x4 u = rt ? u1 : u0;
            float4 o;
            if (keepS[wid][t]) { o.x = u[0]; o.y = u[1]; o.z = u[2]; o.w = u[3]; }
            else o = mv4;
            short4_ sv;
            sv.x = f2bf(o.x); sv.y = f2bf(o.y); sv.z = f2bf(o.z); sv.w = f2bf(o.w);
            *(short4_*)&ctx[((size_t)(b * N_ + n) * T_ + t) * C_ + h * D_ + lk * 4] = sv;
        }
    }
}

// ---------------- kernel 3: fused tail (round-14 champion: 32 rows / 256 thr / 25 KB).
// launch_bounds min-waves MUST stay 4: declaring 6 caps VGPR at 85 -> allocator
// collapses to 40 VGPR + ~300 MB scratch spill (rounds 11 & 13, twice confirmed).
__global__ __launch_bounds__(256, 4) void k_tail(
    const short* __restrict__ ctx, const short* __restrict__ wof, const float* __restrict__ bo,
    const float* __restrict__ query, const float* __restrict__ tepe,
    const float* __restrict__ g1, const float* __restrict__ b1,
    const short* __restrict__ w1f, const float* __restrict__ b1f,
    const short* __restrict__ w2f, const float* __restrict__ b2f,
    const float* __restrict__ g2, const float* __restrict__ b2ln,
    float* __restrict__ out) {
    __shared__ __align__(16) char smem[25088];
    float (*xf)[132] = (float(*)[132])smem;             // phases 0-2
    short* hbf = (short*)smem;                          // phases 3-6, row stride 256
    float (*yf)[132] = (float(*)[132])smem;             // phases 7-8
    short* cbf = (short*)(smem + 16896);                // phases 0-1
    short* x1bf = (short*)(smem + 16896);               // phases 2-7 (cbf dead)
    int tid = threadIdx.x;
    int r0 = blockIdx.x * BMT;
    // ---- phase 0: stage ctx -> cbf, query+tepe -> xf
    {
        int row = tid >> 3;                 // 0..31
        int cb = (tid & 7) * 16;
        int gr = r0 + row;
        int t = gr % T_;
        int b = gr / (N_ * T_);
        const short* csrc = ctx + (size_t)gr * C_ + cb;
        const float* qsrc = query + (size_t)gr * C_ + cb;
        const float* tsrc = tepe + (size_t)(b * T_ + t) * C_ + cb;
        int swz0 = (row & 7) << 3;
        *(short8*)&cbf[(row * C_ + cb) ^ swz0] = *(const short8*)csrc;
        *(short8*)&cbf[(row * C_ + cb + 8) ^ swz0] = *(const short8*)(csrc + 8);
#pragma unroll
        for (int i = 0; i < 4; i++) {
            float4 q4 = *(const float4*)(qsrc + 4 * i);
            float4 t4 = *(const float4*)(tsrc + 4 * i);
            float4 xr;
            xr.x = q4.x + t4.x; xr.y = q4.y + t4.y;
            xr.z = q4.z + t4.z; xr.w = q4.w + t4.w;
            *(float4*)&xf[row][cb + 4 * i] = xr;
        }
    }
    __syncthreads();
    int w = tid >> 6, l = tid & 63;
    int lr = l & 15, lk = l >> 4;
    int swz = (lr & 7) << 3;
    // ---- phase 1: Wo GEMM; wave w owns c-tiles {2w, 2w+1} x both row-tiles
    {
#pragma unroll
        for (int ct = 0; ct < 2; ct++) {
            int c_tile = w * 2 + ct;
            const short* ap = wof + (size_t)c_tile * 2048 + l * 8;
            short8 acur[4];
#pragma unroll
            for (int ks = 0; ks < 4; ks++) acur[ks] = *(const short8*)(ap + ks * 512);
            f32x4 acc[2] = {{0.f, 0.f, 0.f, 0.f}, {0.f, 0.f, 0.f, 0.f}};
#pragma unroll
            for (int ks = 0; ks < 4; ks++) {
#pragma unroll
                for (int rt = 0; rt < 2; rt++) {
                    short8 bc = *(const short8*)&cbf[((rt * 16 + lr) * C_ + ks * 32 + lk * 8) ^ swz];
                    acc[rt] = __builtin_amdgcn_mfma_f32_16x16x32_bf16(acur[ks], bc, acc[rt], 0, 0, 0);
                }
            }
            int cc = c_tile * 16 + lk * 4;
            float4 bias = *(const float4*)(bo + cc);
#pragma unroll
            for (int rt = 0; rt < 2; rt++) {
                int rr = rt * 16 + lr;
                float4 res = *(const float4*)&xf[rr][cc];
                float4 o;
                o.x = acc[rt][0] + bias.x + res.x;
                o.y = acc[rt][1] + bias.y + res.y;
                o.z = acc[rt][2] + bias.z + res.z;
                o.w = acc[rt][3] + bias.w + res.w;
                *(float4*)&xf[rr][cc] = o;
            }
        }
    }
    __syncthreads();
    // ---- phase 2: LN1 -> x1bf (bf16, swizzled; cbf dead)
    {
        int r = tid >> 3;
        int q = tid & 7;
        int cb = q * 16;
        float vals[16];
        float s = 0.f;
#pragma unroll
        for (int i = 0; i < 16; i++) { vals[i] = xf[r][cb + i]; s += vals[i]; }
        s += __shfl_xor(s, 1, 8);
        s += __shfl_xor(s, 2, 8);
        s += __shfl_xor(s, 4, 8);
        float mean = s * (1.f / C_);
        float vv = 0.f;
#pragma unroll
        for (int i = 0; i < 16; i++) { float d = vals[i] - mean; vv += d * d; }
        vv += __shfl_xor(vv, 1, 8);
        vv += __shfl_xor(vv, 2, 8);
        vv += __shfl_xor(vv, 4, 8);
        float rstd = rsqrtf(vv * (1.f / C_) + 1e-5f);
        short8 o0, o1;
#pragma unroll
        for (int i = 0; i < 8; i++) {
            o0[i] = f2bf((vals[i] - mean) * rstd * g1[cb + i] + b1[cb + i]);
            o1[i] = f2bf((vals[8 + i] - mean) * rstd * g1[cb + 8 + i] + b1[cb + 8 + i]);
        }
        int swz0 = (r & 7) << 3;
        *(short8*)&x1bf[(r * C_ + cb) ^ swz0] = o0;
        *(short8*)&x1bf[(r * C_ + cb + 8) ^ swz0] = o1;
    }
    __syncthreads();    // xf dead from here; hbf may overwrite R1
    // ---- phases 3-6: FF in two K-half passes (hbf = 16 KB, j-half at a time)
    f32x4 acc2[2][2] = {{{0.f, 0.f, 0.f, 0.f}, {0.f, 0.f, 0.f, 0.f}},
                        {{0.f, 0.f, 0.f, 0.f}, {0.f, 0.f, 0.f, 0.f}}};
    for (int p = 0; p < 2; p++) {
        {
            short8 bx[2][4];
#pragma unroll
            for (int rt = 0; rt < 2; rt++)
#pragma unroll
                for (int ks = 0; ks < 4; ks++)
                    bx[rt][ks] = *(const short8*)&x1bf[((rt * 16 + lr) * C_ + ks * 32 + lk * 8) ^ swz];
#pragma unroll
            for (int jt = 0; jt < 4; jt++) {
                int jtile = p * 16 + w * 4 + jt;      // global jtile 0..31
                const short* ap = w1f + (size_t)jtile * 2048 + l * 8;
                short8 acur[4];
#pragma unroll
                for (int ks = 0; ks < 4; ks++) acur[ks] = *(const short8*)(ap + ks * 512);
                f32x4 acc[2] = {{0.f, 0.f, 0.f, 0.f}, {0.f, 0.f, 0.f, 0.f}};
#pragma unroll
                for (int ks = 0; ks < 4; ks++) {
#pragma unroll
                    for (int rt = 0; rt < 2; rt++)
                        acc[rt] = __builtin_amdgcn_mfma_f32_16x16x32_bf16(acur[ks], bx[rt][ks], acc[rt], 0, 0, 0);
                }
                int j0g = jtile * 16 + lk * 4;        // global j for bias
                int j0l = (w * 4 + jt) * 16 + lk * 4; // local j for hbf
                float4 bias = *(const float4*)(b1f + j0g);
#pragma unroll
                for (int rt = 0; rt < 2; rt++) {
                    int rr = rt * 16 + lr;
                    short4_ hv;
                    hv.x = f2bf(fmaxf(acc[rt][0] + bias.x, 0.f));
                    hv.y = f2bf(fmaxf(acc[rt][1] + bias.y, 0.f));
                    hv.z = f2bf(fmaxf(acc[rt][2] + bias.z, 0.f));
                    hv.w = f2bf(fmaxf(acc[rt][3] + bias.w, 0.f));
                    *(short4_*)&hbf[(rr * 256 + j0l) ^ swz] = hv;
                }
            }
        }
        __syncthreads();
#pragma unroll 2
        for (int ks = 0; ks < 8; ks++) {
#pragma unroll
            for (int ct = 0; ct < 2; ct++) {
                short8 aw = *(const short8*)(w2f + ((size_t)((w * 2 + ct) * 16 + p * 8 + ks)) * 512 + l * 8);
#pragma unroll
                for (int rt = 0; rt < 2; rt++) {
                    short8 hx = *(const short8*)&hbf[((rt * 16 + lr) * 256 + ks * 32 + lk * 8) ^ swz];
                    acc2[ct][rt] = __builtin_amdgcn_mfma_f32_16x16x32_bf16(aw, hx, acc2[ct][rt], 0, 0, 0);
                }
            }
        }
        __syncthreads();
    }
    // ---- phase 7: y2 = acc2 + bias + residual(x1bf) -> yf
    {
#pragma unroll
        for (int ct = 0; ct < 2; ct++) {
            int cc = (w * 2 + ct) * 16 + lk * 4;
            float4 bias2 = *(const float4*)(b2f + cc);
#pragma unroll
            for (int rt = 0; rt < 2; rt++) {
                int rr = rt * 16 + lr;
                short4_ rb = *(const short4_*)&x1bf[(rr * C_ + cc) ^ swz];
                float4 o;
                o.x = acc2[ct][rt][0] + bias2.x + bf2f(rb.x);
                o.y = acc2[ct][rt][1] + bias2.y + bf2f(rb.y);
                o.z = acc2[ct][rt][2] + bias2.z + bf2f(rb.z);
                o.w = acc2[ct][rt][3] + bias2.w + bf2f(rb.w);
                *(float4*)&yf[rr][cc] = o;
            }
        }
    }
    __syncthreads();
    // ---- phase 8: LN2 + store
    {
        int r = tid >> 3;
        int q = tid & 7;
        int cb = q * 16;
        float vals[16];
        float s = 0.f;
#pragma unroll
        for (int i = 0; i < 16; i++) { vals[i] = yf[r][cb + i]; s += vals[i]; }
        s += __shfl_xor(s, 1, 8);
        s += __shfl_xor(s, 2, 8);
        s += __shfl_xor(s, 4, 8);
        float mean = s * (1.f / C_);
        float vv = 0.f;
#pragma unroll
        for (int i = 0; i < 16; i++) { float d = vals[i] - mean; vv += d * d; }
        vv += __shfl_xor(vv, 1, 8);
        vv += __shfl_xor(vv, 2, 8);
        vv += __shfl_xor(vv, 4, 8);
        float rstd = rsqrtf(vv * (1.f / C_) + 1e-5f);
        float* op = out + (size_t)(r0 + r) * C_ + cb;
#pragma unroll
        for (int i4 = 0; i4 < 4; i4++) {
            float4 gv = *(const float4*)(g2 + cb + 4 * i4);
            float4 bv = *(const float4*)(b2ln + cb + 4 * i4);
            float4 ov;
            ov.x = (vals[4 * i4 + 0] - mean) * rstd * gv.x + bv.x;
            ov.y = (vals[4 * i4 + 1] - mean) * rstd * gv.y + bv.y;
            ov.z = (vals[4 * i4 + 2] - mean) * rstd * gv.z + bv.z;
            ov.w = (vals[4 * i4 + 3] - mean) * rstd * gv.w + bv.w;
            *(float4*)(op + 4 * i4) = ov;
        }
    }
}

extern "C" void kernel_launch(void* const* d_in, const int* in_sizes, int n_in,
                              void* d_out, int out_size, void* d_ws, size_t ws_size,
                              hipStream_t stream) {
    const float* query = (const float*)d_in[2];
    const int* time_enc = (const int*)d_in[4];
    const int* index_sample = (const int*)d_in[5];
    const float* e_min = (const float*)d_in[6];
    const float* e_hr  = (const float*)d_in[7];
    const float* e_wd  = (const float*)d_in[8];
    const float* e_mo  = (const float*)d_in[9];
    const float* e_yr  = (const float*)d_in[10];
    const float* Wq = (const float*)d_in[11];
    const float* Wk = (const float*)d_in[12];
    const float* Wv = (const float*)d_in[13];
    const float* Wo = (const float*)d_in[14];
    const float* bo = (const float*)d_in[15];
    const float* ffw1 = (const float*)d_in[16];
    const float* ffb1 = (const float*)d_in[17];
    const float* ffw2 = (const float*)d_in[18];
    const float* ffb2 = (const float*)d_in[19];
    const float* ln1g = (const float*)d_in[20];
    const float* ln1b = (const float*)d_in[21];
    const float* ln2g = (const float*)d_in[22];
    const float* ln2b = (const float*)d_in[23];

    float* ws = (float*)d_ws;
    float* tepe = ws;                     // TEPE_N floats
    float* region1 = ws + TEPE_N;         // NX floats: bf16 Q
    float* region2 = region1 + NX;        // NX floats: bf16 K, then w1f/w2f/wof
    float* region3 = region2 + NX;        // NX floats: bf16 V
    float* region4 = region3 + NX;        // NX floats: bf16 ctx + wqkvf + cntg

    short* Qb = (short*)region1;
    short* Kb = (short*)region2;
    short* Vb = (short*)region3;
    short* ctxb = (short*)region4;
    short* wqkvf = (short*)region4 + NX;        // dead after qkv
    unsigned char* cntg = (unsigned char*)((short*)region4 + NX + 49152);  // 768 B
    short* w1f = (short*)region2;               // K dead after attn
    short* w2f = w1f + C_ * FF;
    short* wof = w2f + C_ * FF;

    k_tepe<<<dim3(TEPE_N / 256), dim3(256), 0, stream>>>(
        time_enc, e_min, e_hr, e_wd, e_mo, e_yr, tepe, index_sample, cntg);
    k_wcvt_qkv<<<dim3(384 * C_ / 256), dim3(256), 0, stream>>>(Wq, Wk, Wv, wqkvf);
    k_qkv_mfma<<<dim3(NBLK_MM), dim3(256), 0, stream>>>(
        query, tepe, wqkvf, Qb, Kb, Vb);
    k_attn<<<dim3(NUNIT / 4), dim3(256), 0, stream>>>(
        Qb, Kb, Vb, cntg, ctxb);
    k_wcvt2<<<dim3((2 * C_ * FF + C_ * C_) / 256), dim3(256), 0, stream>>>(
        ffw1, ffw2, Wo, w1f, w2f, wof);
    k_tail<<<dim3(NBLK_T), dim3(256), 0, stream>>>(
        ctxb, wof, bo, query, tepe, ln1g, ln1b,
        w1f, ffb1, w2f, ffb2, ln2g, ln2b, (float*)d_out);
}

// Round 21
// 163.858 us; speedup vs baseline: 1.1337x; 1.0319x over previous
//
#include <hip/hip_runtime.h>
#include <hip/hip_bf16.h>
#include <cmath>

namespace {
constexpr int B_ = 16, N_ = 307, T_ = 24, C_ = 128, H_ = 8, D_ = 16, S_ = 20, U_ = 20;
constexpr int NROW = B_ * N_ * T_;          // 117888
constexpr int NX = NROW * C_;               // 15089664
constexpr int TEPE_N = B_ * T_ * C_;        // 49152
constexpr int FF = 4 * C_;                  // 512
constexpr int BM = 32;                      // rows per qkv block
constexpr int NBLK_MM = NROW / BM;          // 3684
constexpr int BMT = 32;                     // rows per tail block (256 thr, 4 waves)
constexpr int NBLK_T = NROW / BMT;          // 3684
constexpr int NUNIT = B_ * H_ * N_;         // 39296
constexpr int PREP_N = TEPE_N + 384 * C_ + (2 * C_ * FF + C_ * C_);  // 245760
}

typedef __attribute__((ext_vector_type(8))) short short8;
typedef __attribute__((ext_vector_type(4))) short short4_;
typedef __attribute__((ext_vector_type(4))) float f32x4;

__device__ inline short f2bf(float v) {
    union { float f; unsigned u; } a; a.f = v;
    unsigned r = a.u + 0x7fff + ((a.u >> 16) & 1);   // round-to-nearest-even
    return (short)(r >> 16);
}
__device__ inline float bf2f(short s) {
    return __bfloat162float(*(const __hip_bfloat16*)&s);
}

// ---------------- kernel 0: merged prep — tepe + all weight converts + cnt table
// (merged from 3 launches; saves ~12 us of dispatch overhead, r17/r19 evidence)
__global__ void k_prep(const int* __restrict__ te,
                       const float* __restrict__ e_min, const float* __restrict__ e_hr,
                       const float* __restrict__ e_wd, const float* __restrict__ e_mo,
                       const float* __restrict__ e_yr, float* __restrict__ tepe,
                       const int* __restrict__ idxs, unsigned char* __restrict__ cntg,
                       const float* __restrict__ Wq, const float* __restrict__ Wk,
                       const float* __restrict__ Wv, short* __restrict__ wqkvf,
                       const float* __restrict__ w1, const float* __restrict__ w2,
                       const float* __restrict__ Wo,
                       short* __restrict__ w1f, short* __restrict__ w2f,
                       short* __restrict__ wof) {
    int i = blockIdx.x * 256 + threadIdx.x;
    if (i < TEPE_N) {
        int c = i & (C_ - 1);
        int bt = i >> 7;              // b*T + t
        int t = bt % T_;
        const int* enc = te + bt * 5;
        float v = e_min[enc[0] * C_ + c] + e_hr[enc[1] * C_ + c] + e_wd[enc[2] * C_ + c]
                + e_mo[enc[3] * C_ + c] + e_yr[enc[4] * C_ + c];
        float ang = (float)t * expf(-(float)(c & ~1) * (9.210340371976184f / 128.0f));
        v += (c & 1) ? cosf(ang) : sinf(ang);
        tepe[i] = v;
    } else if (i < TEPE_N + 384 * C_) {
        int j = i - TEPE_N;                 // wqkvf, frag-linear
        int tile = j >> 9, l = (j >> 3) & 63, e = j & 7;
        int c_tile = tile >> 2, ks = tile & 3;
        int c_all = c_tile * 16 + (l & 15);
        int k = ks * 32 + (l >> 4) * 8 + e;
        int m = c_all >> 7, c = c_all & (C_ - 1);
        const float* W = (m == 0) ? Wq : (m == 1) ? Wk : Wv;
        wqkvf[j] = f2bf(W[k * C_ + c]);
    } else {
        int j = i - TEPE_N - 384 * C_;      // w1f / w2f / wof, frag-linear
        if (j < C_ * FF) {
            int tile = j >> 9, l = (j >> 3) & 63, e = j & 7;
            int jtile = tile >> 2, ks = tile & 3;
            int jj = jtile * 16 + (l & 15);
            int k = ks * 32 + (l >> 4) * 8 + e;
            w1f[j] = f2bf(w1[k * FF + jj]);
        } else if (j < 2 * C_ * FF) {
            int j2 = j - C_ * FF;
            int tile = j2 >> 9, l = (j2 >> 3) & 63, e = j2 & 7;
            int c_tile = tile >> 4, ks = tile & 15;
            int c = c_tile * 16 + (l & 15);
            int jj = ks * 32 + (l >> 4) * 8 + e;
            w2f[j2] = f2bf(w2[jj * C_ + c]);
        } else {
            int j3 = j - 2 * C_ * FF;
            int tile = j3 >> 9, l = (j3 >> 3) & 63, e = j3 & 7;
            int c_tile = tile >> 2, ks = tile & 3;
            int c = c_tile * 16 + (l & 15);
            int k = ks * 32 + (l >> 4) * 8 + e;
            wof[j3] = f2bf(Wo[k * C_ + c]);
        }
    }
    if (blockIdx.x == 0) {      // build cnt[24][32] once (shared by all attn blocks)
        __shared__ int scnt[T_ * 32];
        for (int j = threadIdx.x; j < T_ * 32; j += 256) scnt[j] = 0;
        __syncthreads();
        for (int j = threadIdx.x; j < T_ * S_; j += 256) {
            int t = j / S_;
            atomicAdd(&scnt[t * 32 + idxs[j]], 1);
        }
        __syncthreads();
        for (int j = threadIdx.x; j < 192; j += 256) {
            unsigned v = (unsigned)scnt[4 * j] | ((unsigned)scnt[4 * j + 1] << 8)
                       | ((unsigned)scnt[4 * j + 2] << 16) | ((unsigned)scnt[4 * j + 3] << 24);
            ((unsigned*)cntg)[j] = v;
        }
    }
}

// ---------------- kernel 1: QKV projection via MFMA (x = query+tepe fused in staging)
__global__ __launch_bounds__(256) void k_qkv_mfma(
    const float* __restrict__ query, const float* __restrict__ tepe,
    const short* __restrict__ wqkvf,
    short* __restrict__ Q, short* __restrict__ K, short* __restrict__ V) {
    __shared__ __align__(16) short xs[BM * C_];
    int tid = threadIdx.x;
    int r0 = blockIdx.x * BM;
    {
        int row = tid >> 3;                 // 0..31
        int cb = (tid & 7) * 16;
        int gr = r0 + row;
        int t = gr % T_;
        int b = gr / (N_ * T_);
        const float* qsrc = query + (size_t)gr * C_ + cb;
        const float* tsrc = tepe + (size_t)(b * T_ + t) * C_ + cb;
        int swz0 = (row & 7) << 3;
#pragma unroll
        for (int i = 0; i < 4; i++) {
            float4 q4 = *(const float4*)(qsrc + 4 * i);
            float4 t4 = *(const float4*)(tsrc + 4 * i);
            short4_ sv;
            sv.x = f2bf(q4.x + t4.x); sv.y = f2bf(q4.y + t4.y);
            sv.z = f2bf(q4.z + t4.z); sv.w = f2bf(q4.w + t4.w);
            *(short4_*)&xs[(row * C_ + cb + 4 * i) ^ swz0] = sv;
        }
    }
    __syncthreads();
    int w = tid >> 6, l = tid & 63;
    int lr = l & 15, lk = l >> 4;
    int swz = (lr & 7) << 3;                // row-tile-invariant swizzle
    short8 bx[2][4];
#pragma unroll
    for (int rt = 0; rt < 2; rt++)
#pragma unroll
        for (int ks = 0; ks < 4; ks++)
            bx[rt][ks] = *(const short8*)&xs[((rt * 16 + lr) * C_ + ks * 32 + lk * 8) ^ swz];
    size_t base[2];
#pragma unroll
    for (int rt = 0; rt < 2; rt++) {
        int gr = r0 + rt * 16 + lr;
        int t = gr % T_;
        int n = (gr / T_) % N_;
        int b = gr / (N_ * T_);
        base[rt] = ((size_t)b * H_ * N_ + n) * (T_ * D_) + t * D_;
    }
#pragma unroll
    for (int jt = 0; jt < 6; jt++) {
        int ctile = w * 6 + jt;                 // c-tile index 0..23
        const short* ap = wqkvf + (size_t)ctile * 2048 + l * 8;
        short8 acur[4];
#pragma unroll
        for (int ks = 0; ks < 4; ks++) acur[ks] = *(const short8*)(ap + ks * 512);
        f32x4 acc[2] = {{0.f, 0.f, 0.f, 0.f}, {0.f, 0.f, 0.f, 0.f}};
#pragma unroll
        for (int ks = 0; ks < 4; ks++) {
#pragma unroll
            for (int rt = 0; rt < 2; rt++)
                acc[rt] = __builtin_amdgcn_mfma_f32_16x16x32_bf16(acur[ks], bx[rt][ks], acc[rt], 0, 0, 0);
        }
        int c0 = ctile * 16 + lk * 4;
        int m = c0 >> 7;
        int c = c0 & (C_ - 1);
        int h = c >> 4, d = c & 15;
        short* dst = (m == 0) ? Q : (m == 1) ? K : V;
#pragma unroll
        for (int rt = 0; rt < 2; rt++) {
            short4_ sv;
            sv.x = f2bf(acc[rt][0]); sv.y = f2bf(acc[rt][1]);
            sv.z = f2bf(acc[rt][2]); sv.w = f2bf(acc[rt][3]);
            *(short4_*)&dst[base[rt] + (size_t)h * (N_ * T_ * D_) + d] = sv;
        }
    }
}

// ---------------- kernel 2: attention, 4 units per 256-thread block (1 wave/unit)
__global__ __launch_bounds__(256) void k_attn(
    const short* __restrict__ Q, const short* __restrict__ K, const short* __restrict__ V,
    const unsigned char* __restrict__ cntg, short* __restrict__ ctx) {
    __shared__ __align__(16) short Qbf[4][32 * 24], Kbf[4][32 * 24];
    __shared__ __align__(16) short Vt[4][16 * 40];       // [d][t2], cols 24-31 zeroed
    __shared__ __align__(16) short Pbf[4][32 * 40];      // attn weights, cols 24-31 zeroed
    __shared__ unsigned char cntS[T_ * 32];              // shared by all 4 units
    __shared__ float Mv[4][T_];
    __shared__ int keepS[4][T_];
    __shared__ float meanVs[4][D_];
    int tid = threadIdx.x;
    int wid = tid >> 6, l = tid & 63;
    int e = blockIdx.x * 4 + wid;
    const short* qb = Q + (size_t)e * (T_ * D_);
    const short* kb = K + (size_t)e * (T_ * D_);
    const short* vb = V + (size_t)e * (T_ * D_);
    if (l < 48) {
        int t = l >> 1, hf = l & 1;
        *(short8*)&Qbf[wid][t * 24 + hf * 8] = *(const short8*)(qb + t * 16 + hf * 8);
        *(short8*)&Kbf[wid][t * 24 + hf * 8] = *(const short8*)(kb + t * 16 + hf * 8);
    }
    for (int i = l; i < 96; i += 64) {
        int t = i >> 2, c4 = i & 3;
        short4_ v = *(const short4_*)(vb + t * 16 + c4 * 4);
        Vt[wid][(c4 * 4 + 0) * 40 + t] = v.x;
        Vt[wid][(c4 * 4 + 1) * 40 + t] = v.y;
        Vt[wid][(c4 * 4 + 2) * 40 + t] = v.z;
        Vt[wid][(c4 * 4 + 3) * 40 + t] = v.w;
    }
    for (int i = l; i < 128; i += 64) {       // zero Vt cols 24-31
        int d = i >> 3, c = 24 + (i & 7);
        Vt[wid][d * 40 + c] = 0;
    }
    if (tid < 192) ((int*)cntS)[tid] = ((const int*)cntg)[tid];
    __syncthreads();
    if (l >= 48) {
        int d = l - 48;
        float s = 0.f;
        for (int t = 0; t < T_; t++) s += bf2f(Vt[wid][d * 40 + t]);
        meanVs[wid][d] = s * (1.0f / T_);
    }
    int lr = l & 15, lk = l >> 4;
    short8 zz = {};
    short8 kf0 = zz, kf1 = zz, qf0 = zz, qf1 = zz;
    if (lk < 2) {
        kf0 = *(const short8*)&Kbf[wid][lr * 24 + lk * 8];
        kf1 = *(const short8*)&Kbf[wid][(16 + lr) * 24 + lk * 8];
        qf0 = *(const short8*)&Qbf[wid][lr * 24 + lk * 8];
        qf1 = *(const short8*)&Qbf[wid][(16 + lr) * 24 + lk * 8];
    }
    f32x4 zf = {0.f, 0.f, 0.f, 0.f};
    f32x4 s00 = __builtin_amdgcn_mfma_f32_16x16x32_bf16(kf0, qf0, zf, 0, 0, 0);
    f32x4 s01 = __builtin_amdgcn_mfma_f32_16x16x32_bf16(kf1, qf0, zf, 0, 0, 0);
    f32x4 s10 = __builtin_amdgcn_mfma_f32_16x16x32_bf16(kf0, qf1, zf, 0, 0, 0);
    f32x4 s11 = __builtin_amdgcn_mfma_f32_16x16x32_bf16(kf1, qf1, zf, 0, 0, 0);
#pragma unroll
    for (int rt = 0; rt < 2; rt++) {
        int t = rt * 16 + lr;
        int tt = (t < T_) ? t : 0;
        f32x4 c0 = rt ? s10 : s00;
        f32x4 c1 = rt ? s11 : s01;
        float mx = -1e30f, sm = 0.f;
#pragma unroll
        for (int i = 0; i < 4; i++) {
            int cA = cntS[tt * 32 + lk * 4 + i];
            if (cA) { mx = fmaxf(mx, c0[i]); sm += (float)cA * c0[i]; }
        }
        if (lk < 2) {
#pragma unroll
            for (int i = 0; i < 4; i++) {
                int cB = cntS[tt * 32 + 16 + lk * 4 + i];
                if (cB) { mx = fmaxf(mx, c1[i]); sm += (float)cB * c1[i]; }
            }
        }
        mx = fmaxf(mx, __shfl_xor(mx, 16));
        mx = fmaxf(mx, __shfl_xor(mx, 32));
        sm += __shfl_xor(sm, 16);
        sm += __shfl_xor(sm, 32);
        if (lk == 0 && t < T_) Mv[wid][t] = mx - sm * (1.0f / S_);
    }
    __syncthreads();
    if (l < T_) {
        float mt = Mv[wid][l];
        int cnt2 = 0;
        for (int t2 = 0; t2 < T_; t2++) {
            float m2 = Mv[wid][t2];
            cnt2 += (m2 > mt) || (m2 == mt && t2 < l);
        }
        keepS[wid][l] = (cnt2 < U_) ? 1 : 0;
    }
#pragma unroll
    for (int rt = 0; rt < 2; rt++) {
        f32x4 c0 = rt ? s10 : s00;
        f32x4 c1 = rt ? s11 : s01;
        float lm = fmaxf(fmaxf(c0[0], c0[1]), fmaxf(c0[2], c0[3]));
        if (lk < 2) lm = fmaxf(lm, fmaxf(fmaxf(c1[0], c1[1]), fmaxf(c1[2], c1[3])));
        lm = fmaxf(lm, __shfl_xor(lm, 16));
        lm = fmaxf(lm, __shfl_xor(lm, 32));
        float e0[4], e1[4];
        float ls = 0.f;
#pragma unroll
        for (int i = 0; i < 4; i++) { e0[i] = __expf(0.25f * (c0[i] - lm)); ls += e0[i]; }
#pragma unroll
        for (int i = 0; i < 4; i++) { e1[i] = (lk < 2) ? __expf(0.25f * (c1[i] - lm)) : 0.f; ls += e1[i]; }
        ls += __shfl_xor(ls, 16);
        ls += __shfl_xor(ls, 32);
        float inv = 1.0f / ls;
        short4_ w0, w1;
        w0.x = f2bf(e0[0] * inv); w0.y = f2bf(e0[1] * inv);
        w0.z = f2bf(e0[2] * inv); w0.w = f2bf(e0[3] * inv);
        w1.x = f2bf(e1[0] * inv); w1.y = f2bf(e1[1] * inv);
        w1.z = f2bf(e1[2] * inv); w1.w = f2bf(e1[3] * inv);
        int trow = rt * 16 + lr;
        *(short4_*)&Pbf[wid][trow * 40 + lk * 4] = w0;
        *(short4_*)&Pbf[wid][trow * 40 + 16 + lk * 4] = w1;   // lk>=2 writes zeros
    }
    __syncthreads();
    short8 vf = *(const short8*)&Vt[wid][lr * 40 + lk * 8];
    short8 pf0 = *(const short8*)&Pbf[wid][lr * 40 + lk * 8];
    short8 pf1 = *(const short8*)&Pbf[wid][(16 + lr) * 40 + lk * 8];
    f32x4 u0 = __builtin_amdgcn_mfma_f32_16x16x32_bf16(vf, pf0, zf, 0, 0, 0);
    f32x4 u1 = __builtin_amdgcn_mfma_f32_16x16x32_bf16(vf, pf1, zf, 0, 0, 0);
    int b = e / (H_ * N_);
    int h = (e / N_) % H_;
    int n = e % N_;
    float4 mv4 = *(const float4*)&meanVs[wid][lk * 4];
#pragma unroll
    for (int rt = 0; rt < 2; rt++) {
        int t = rt * 16 + lr;
        if (t < T_) {
            f32x4 u = rt ? u1 : u0;
            float4 o;
            if (keepS[wid][t]) { o.x = u[0]; o.y = u[1]; o.z = u[2]; o.w = u[3]; }
            else o = mv4;
            short4_ sv;
            sv.x = f2bf(o.x); sv.y = f2bf(o.y); sv.z = f2bf(o.z); sv.w = f2bf(o.w);
            *(short4_*)&ctx[((size_t)(b * N_ + n) * T_ + t) * C_ + h * D_ + lk * 4] = sv;
        }
    }
}

// ---------------- kernel 3: fused tail (round-14 champion: 32 rows / 256 thr / 25 KB).
// launch_bounds min-waves MUST stay 4: declaring 6 caps VGPR at 85 -> allocator
// collapses to 40 VGPR + ~300 MB scratch spill (rounds 11 & 13, twice confirmed).
__global__ __launch_bounds__(256, 4) void k_tail(
    const short* __restrict__ ctx, const short* __restrict__ wof, const float* __restrict__ bo,
    const float* __restrict__ query, const float* __restrict__ tepe,
    const float* __restrict__ g1, const float* __restrict__ b1,
    const short* __restrict__ w1f, const float* __restrict__ b1f,
    const short* __restrict__ w2f, const float* __restrict__ b2f,
    const float* __restrict__ g2, const float* __restrict__ b2ln,
    float* __restrict__ out) {
    __shared__ __align__(16) char smem[25088];
    float (*xf)[132] = (float(*)[132])smem;             // phases 0-2
    short* hbf = (short*)smem;                          // phases 3-6, row stride 256
    float (*yf)[132] = (float(*)[132])smem;             // phases 7-8
    short* cbf = (short*)(smem + 16896);                // phases 0-1
    short* x1bf = (short*)(smem + 16896);               // phases 2-7 (cbf dead)
    int tid = threadIdx.x;
    int r0 = blockIdx.x * BMT;
    // ---- phase 0: stage ctx -> cbf, query+tepe -> xf
    {
        int row = tid >> 3;                 // 0..31
        int cb = (tid & 7) * 16;
        int gr = r0 + row;
        int t = gr % T_;
        int b = gr / (N_ * T_);
        const short* csrc = ctx + (size_t)gr * C_ + cb;
        const float* qsrc = query + (size_t)gr * C_ + cb;
        const float* tsrc = tepe + (size_t)(b * T_ + t) * C_ + cb;
        int swz0 = (row & 7) << 3;
        *(short8*)&cbf[(row * C_ + cb) ^ swz0] = *(const short8*)csrc;
        *(short8*)&cbf[(row * C_ + cb + 8) ^ swz0] = *(const short8*)(csrc + 8);
#pragma unroll
        for (int i = 0; i < 4; i++) {
            float4 q4 = *(const float4*)(qsrc + 4 * i);
            float4 t4 = *(const float4*)(tsrc + 4 * i);
            float4 xr;
            xr.x = q4.x + t4.x; xr.y = q4.y + t4.y;
            xr.z = q4.z + t4.z; xr.w = q4.w + t4.w;
            *(float4*)&xf[row][cb + 4 * i] = xr;
        }
    }
    __syncthreads();
    int w = tid >> 6, l = tid & 63;
    int lr = l & 15, lk = l >> 4;
    int swz = (lr & 7) << 3;
    // ---- phase 1: Wo GEMM; wave w owns c-tiles {2w, 2w+1} x both row-tiles
    {
#pragma unroll
        for (int ct = 0; ct < 2; ct++) {
            int c_tile = w * 2 + ct;
            const short* ap = wof + (size_t)c_tile * 2048 + l * 8;
            short8 acur[4];
#pragma unroll
            for (int ks = 0; ks < 4; ks++) acur[ks] = *(const short8*)(ap + ks * 512);
            f32x4 acc[2] = {{0.f, 0.f, 0.f, 0.f}, {0.f, 0.f, 0.f, 0.f}};
#pragma unroll
            for (int ks = 0; ks < 4; ks++) {
#pragma unroll
                for (int rt = 0; rt < 2; rt++) {
                    short8 bc = *(const short8*)&cbf[((rt * 16 + lr) * C_ + ks * 32 + lk * 8) ^ swz];
                    acc[rt] = __builtin_amdgcn_mfma_f32_16x16x32_bf16(acur[ks], bc, acc[rt], 0, 0, 0);
                }
            }
            int cc = c_tile * 16 + lk * 4;
            float4 bias = *(const float4*)(bo + cc);
#pragma unroll
            for (int rt = 0; rt < 2; rt++) {
                int rr = rt * 16 + lr;
                float4 res = *(const float4*)&xf[rr][cc];
                float4 o;
                o.x = acc[rt][0] + bias.x + res.x;
                o.y = acc[rt][1] + bias.y + res.y;
                o.z = acc[rt][2] + bias.z + res.z;
                o.w = acc[rt][3] + bias.w + res.w;
                *(float4*)&xf[rr][cc] = o;
            }
        }
    }
    __syncthreads();
    // ---- phase 2: LN1 -> x1bf (bf16, swizzled; cbf dead)
    {
        int r = tid >> 3;
        int q = tid & 7;
        int cb = q * 16;
        float vals[16];
        float s = 0.f;
#pragma unroll
        for (int i = 0; i < 16; i++) { vals[i] = xf[r][cb + i]; s += vals[i]; }
        s += __shfl_xor(s, 1, 8);
        s += __shfl_xor(s, 2, 8);
        s += __shfl_xor(s, 4, 8);
        float mean = s * (1.f / C_);
        float vv = 0.f;
#pragma unroll
        for (int i = 0; i < 16; i++) { float d = vals[i] - mean; vv += d * d; }
        vv += __shfl_xor(vv, 1, 8);
        vv += __shfl_xor(vv, 2, 8);
        vv += __shfl_xor(vv, 4, 8);
        float rstd = rsqrtf(vv * (1.f / C_) + 1e-5f);
        short8 o0, o1;
#pragma unroll
        for (int i = 0; i < 8; i++) {
            o0[i] = f2bf((vals[i] - mean) * rstd * g1[cb + i] + b1[cb + i]);
            o1[i] = f2bf((vals[8 + i] - mean) * rstd * g1[cb + 8 + i] + b1[cb + 8 + i]);
        }
        int swz0 = (r & 7) << 3;
        *(short8*)&x1bf[(r * C_ + cb) ^ swz0] = o0;
        *(short8*)&x1bf[(r * C_ + cb + 8) ^ swz0] = o1;
    }
    __syncthreads();    // xf dead from here; hbf may overwrite R1
    // ---- phases 3-6: FF in two K-half passes (hbf = 16 KB, j-half at a time)
    f32x4 acc2[2][2] = {{{0.f, 0.f, 0.f, 0.f}, {0.f, 0.f, 0.f, 0.f}},
                        {{0.f, 0.f, 0.f, 0.f}, {0.f, 0.f, 0.f, 0.f}}};
    for (int p = 0; p < 2; p++) {
        {
            short8 bx[2][4];
#pragma unroll
            for (int rt = 0; rt < 2; rt++)
#pragma unroll
                for (int ks = 0; ks < 4; ks++)
                    bx[rt][ks] = *(const short8*)&x1bf[((rt * 16 + lr) * C_ + ks * 32 + lk * 8) ^ swz];
#pragma unroll
            for (int jt = 0; jt < 4; jt++) {
                int jtile = p * 16 + w * 4 + jt;      // global jtile 0..31
                const short* ap = w1f + (size_t)jtile * 2048 + l * 8;
                short8 acur[4];
#pragma unroll
                for (int ks = 0; ks < 4; ks++) acur[ks] = *(const short8*)(ap + ks * 512);
                f32x4 acc[2] = {{0.f, 0.f, 0.f, 0.f}, {0.f, 0.f, 0.f, 0.f}};
#pragma unroll
                for (int ks = 0; ks < 4; ks++) {
#pragma unroll
                    for (int rt = 0; rt < 2; rt++)
                        acc[rt] = __builtin_amdgcn_mfma_f32_16x16x32_bf16(acur[ks], bx[rt][ks], acc[rt], 0, 0, 0);
                }
                int j0g = jtile * 16 + lk * 4;        // global j for bias
                int j0l = (w * 4 + jt) * 16 + lk * 4; // local j for hbf
                float4 bias = *(const float4*)(b1f + j0g);
#pragma unroll
                for (int rt = 0; rt < 2; rt++) {
                    int rr = rt * 16 + lr;
                    short4_ hv;
                    hv.x = f2bf(fmaxf(acc[rt][0] + bias.x, 0.f));
                    hv.y = f2bf(fmaxf(acc[rt][1] + bias.y, 0.f));
                    hv.z = f2bf(fmaxf(acc[rt][2] + bias.z, 0.f));
                    hv.w = f2bf(fmaxf(acc[rt][3] + bias.w, 0.f));
                    *(short4_*)&hbf[(rr * 256 + j0l) ^ swz] = hv;
                }
            }
        }
        __syncthreads();
#pragma unroll 2
        for (int ks = 0; ks < 8; ks++) {
#pragma unroll
            for (int ct = 0; ct < 2; ct++) {
                short8 aw = *(const short8*)(w2f + ((size_t)((w * 2 + ct) * 16 + p * 8 + ks)) * 512 + l * 8);
#pragma unroll
                for (int rt = 0; rt < 2; rt++) {
                    short8 hx = *(const short8*)&hbf[((rt * 16 + lr) * 256 + ks * 32 + lk * 8) ^ swz];
                    acc2[ct][rt] = __builtin_amdgcn_mfma_f32_16x16x32_bf16(aw, hx, acc2[ct][rt], 0, 0, 0);
                }
            }
        }
        __syncthreads();
    }
    // ---- phase 7: y2 = acc2 + bias + residual(x1bf) -> yf
    {
#pragma unroll
        for (int ct = 0; ct < 2; ct++) {
            int cc = (w * 2 + ct) * 16 + lk * 4;
            float4 bias2 = *(const float4*)(b2f + cc);
#pragma unroll
            for (int rt = 0; rt < 2; rt++) {
                int rr = rt * 16 + lr;
                short4_ rb = *(const short4_*)&x1bf[(rr * C_ + cc) ^ swz];
                float4 o;
                o.x = acc2[ct][rt][0] + bias2.x + bf2f(rb.x);
                o.y = acc2[ct][rt][1] + bias2.y + bf2f(rb.y);
                o.z = acc2[ct][rt][2] + bias2.z + bf2f(rb.z);
                o.w = acc2[ct][rt][3] + bias2.w + bf2f(rb.w);
                *(float4*)&yf[rr][cc] = o;
            }
        }
    }
    __syncthreads();
    // ---- phase 8: LN2 + store
    {
        int r = tid >> 3;
        int q = tid & 7;
        int cb = q * 16;
        float vals[16];
        float s = 0.f;
#pragma unroll
        for (int i = 0; i < 16; i++) { vals[i] = yf[r][cb + i]; s += vals[i]; }
        s += __shfl_xor(s, 1, 8);
        s += __shfl_xor(s, 2, 8);
        s += __shfl_xor(s, 4, 8);
        float mean = s * (1.f / C_);
        float vv = 0.f;
#pragma unroll
        for (int i = 0; i < 16; i++) { float d = vals[i] - mean; vv += d * d; }
        vv += __shfl_xor(vv, 1, 8);
        vv += __shfl_xor(vv, 2, 8);
        vv += __shfl_xor(vv, 4, 8);
        float rstd = rsqrtf(vv * (1.f / C_) + 1e-5f);
        float* op = out + (size_t)(r0 + r) * C_ + cb;
#pragma unroll
        for (int i4 = 0; i4 < 4; i4++) {
            float4 gv = *(const float4*)(g2 + cb + 4 * i4);
            float4 bv = *(const float4*)(b2ln + cb + 4 * i4);
            float4 ov;
            ov.x = (vals[4 * i4 + 0] - mean) * rstd * gv.x + bv.x;
            ov.y = (vals[4 * i4 + 1] - mean) * rstd * gv.y + bv.y;
            ov.z = (vals[4 * i4 + 2] - mean) * rstd * gv.z + bv.z;
            ov.w = (vals[4 * i4 + 3] - mean) * rstd * gv.w + bv.w;
            *(float4*)(op + 4 * i4) = ov;
        }
    }
}

extern "C" void kernel_launch(void* const* d_in, const int* in_sizes, int n_in,
                              void* d_out, int out_size, void* d_ws, size_t ws_size,
                              hipStream_t stream) {
    const float* query = (const float*)d_in[2];
    const int* time_enc = (const int*)d_in[4];
    const int* index_sample = (const int*)d_in[5];
    const float* e_min = (const float*)d_in[6];
    const float* e_hr  = (const float*)d_in[7];
    const float* e_wd  = (const float*)d_in[8];
    const float* e_mo  = (const float*)d_in[9];
    const float* e_yr  = (const float*)d_in[10];
    const float* Wq = (const float*)d_in[11];
    const float* Wk = (const float*)d_in[12];
    const float* Wv = (const float*)d_in[13];
    const float* Wo = (const float*)d_in[14];
    const float* bo = (const float*)d_in[15];
    const float* ffw1 = (const float*)d_in[16];
    const float* ffb1 = (const float*)d_in[17];
    const float* ffw2 = (const float*)d_in[18];
    const float* ffb2 = (const float*)d_in[19];
    const float* ln1g = (const float*)d_in[20];
    const float* ln1b = (const float*)d_in[21];
    const float* ln2g = (const float*)d_in[22];
    const float* ln2b = (const float*)d_in[23];

    float* ws = (float*)d_ws;
    float* tepe = ws;                     // TEPE_N floats
    float* region1 = ws + TEPE_N;         // NX floats: bf16 Q
    float* region2 = region1 + NX;        // NX floats: bf16 K (1st half) + w1f/w2f/wof (2nd half)
    float* region3 = region2 + NX;        // NX floats: bf16 V
    float* region4 = region3 + NX;        // NX floats: bf16 ctx + wqkvf + cntg

    short* Qb = (short*)region1;
    short* Kb = (short*)region2;
    short* Vb = (short*)region3;
    short* ctxb = (short*)region4;
    short* wqkvf = (short*)region4 + NX;        // dead after qkv
    unsigned char* cntg = (unsigned char*)((short*)region4 + NX + 49152);  // 768 B
    short* w1f = (short*)region2 + NX;          // region2 second half (K uses first; r19-proven)
    short* w2f = w1f + C_ * FF;
    short* wof = w2f + C_ * FF;

    k_prep<<<dim3(PREP_N / 256), dim3(256), 0, stream>>>(
        time_enc, e_min, e_hr, e_wd, e_mo, e_yr, tepe, index_sample, cntg,
        Wq, Wk, Wv, wqkvf, ffw1, ffw2, Wo, w1f, w2f, wof);
    k_qkv_mfma<<<dim3(NBLK_MM), dim3(256), 0, stream>>>(
        query, tepe, wqkvf, Qb, Kb, Vb);
    k_attn<<<dim3(NUNIT / 4), dim3(256), 0, stream>>>(
        Qb, Kb, Vb, cntg, ctxb);
    k_tail<<<dim3(NBLK_T), dim3(256), 0, stream>>>(
        ctxb, wof, bo, query, tepe, ln1g, ln1b,
        w1f, ffb1, w2f, ffb2, ln2g, ln2b, (float*)d_out);
}

// Round 22
// 162.051 us; speedup vs baseline: 1.1463x; 1.0111x over previous
//
#include <hip/hip_runtime.h>
#include <hip/hip_bf16.h>
#include <cmath>

namespace {
constexpr int B_ = 16, N_ = 307, T_ = 24, C_ = 128, H_ = 8, D_ = 16, S_ = 20, U_ = 20;
constexpr int NROW = B_ * N_ * T_;          // 117888
constexpr int NX = NROW * C_;               // 15089664
constexpr int TEPE_N = B_ * T_ * C_;        // 49152
constexpr int FF = 4 * C_;                  // 512
constexpr int BM = 32;                      // rows per qkv block
constexpr int NBLK_MM = NROW / BM;          // 3684
constexpr int BMT = 32;                     // rows per tail block (256 thr, 4 waves)
constexpr int NBLK_T = NROW / BMT;          // 3684
constexpr int NUNIT = B_ * H_ * N_;         // 39296
constexpr int PREP_N = TEPE_N + 384 * C_ + (2 * C_ * FF + C_ * C_);  // 245760
}

typedef __attribute__((ext_vector_type(8))) short short8;
typedef __attribute__((ext_vector_type(4))) short short4_;
typedef __attribute__((ext_vector_type(4))) float f32x4;

__device__ inline short f2bf(float v) {
    union { float f; unsigned u; } a; a.f = v;
    unsigned r = a.u + 0x7fff + ((a.u >> 16) & 1);   // round-to-nearest-even
    return (short)(r >> 16);
}
__device__ inline float bf2f(short s) {
    return __bfloat162float(*(const __hip_bfloat16*)&s);
}

// ---------------- kernel 0: merged prep — tepe + all weight converts + cnt table
__global__ void k_prep(const int* __restrict__ te,
                       const float* __restrict__ e_min, const float* __restrict__ e_hr,
                       const float* __restrict__ e_wd, const float* __restrict__ e_mo,
                       const float* __restrict__ e_yr, float* __restrict__ tepe,
                       const int* __restrict__ idxs, unsigned char* __restrict__ cntg,
                       const float* __restrict__ Wq, const float* __restrict__ Wk,
                       const float* __restrict__ Wv, short* __restrict__ wqkvf,
                       const float* __restrict__ w1, const float* __restrict__ w2,
                       const float* __restrict__ Wo,
                       short* __restrict__ w1f, short* __restrict__ w2f,
                       short* __restrict__ wof) {
    int i = blockIdx.x * 256 + threadIdx.x;
    if (i < TEPE_N) {
        int c = i & (C_ - 1);
        int bt = i >> 7;              // b*T + t
        int t = bt % T_;
        const int* enc = te + bt * 5;
        float v = e_min[enc[0] * C_ + c] + e_hr[enc[1] * C_ + c] + e_wd[enc[2] * C_ + c]
                + e_mo[enc[3] * C_ + c] + e_yr[enc[4] * C_ + c];
        float ang = (float)t * expf(-(float)(c & ~1) * (9.210340371976184f / 128.0f));
        v += (c & 1) ? cosf(ang) : sinf(ang);
        tepe[i] = v;
    } else if (i < TEPE_N + 384 * C_) {
        int j = i - TEPE_N;                 // wqkvf, frag-linear
        int tile = j >> 9, l = (j >> 3) & 63, e = j & 7;
        int c_tile = tile >> 2, ks = tile & 3;
        int c_all = c_tile * 16 + (l & 15);
        int k = ks * 32 + (l >> 4) * 8 + e;
        int m = c_all >> 7, c = c_all & (C_ - 1);
        const float* W = (m == 0) ? Wq : (m == 1) ? Wk : Wv;
        wqkvf[j] = f2bf(W[k * C_ + c]);
    } else {
        int j = i - TEPE_N - 384 * C_;      // w1f / w2f / wof, frag-linear
        if (j < C_ * FF) {
            int tile = j >> 9, l = (j >> 3) & 63, e = j & 7;
            int jtile = tile >> 2, ks = tile & 3;
            int jj = jtile * 16 + (l & 15);
            int k = ks * 32 + (l >> 4) * 8 + e;
            w1f[j] = f2bf(w1[k * FF + jj]);
        } else if (j < 2 * C_ * FF) {
            int j2 = j - C_ * FF;
            int tile = j2 >> 9, l = (j2 >> 3) & 63, e = j2 & 7;
            int c_tile = tile >> 4, ks = tile & 15;
            int c = c_tile * 16 + (l & 15);
            int jj = ks * 32 + (l >> 4) * 8 + e;
            w2f[j2] = f2bf(w2[jj * C_ + c]);
        } else {
            int j3 = j - 2 * C_ * FF;
            int tile = j3 >> 9, l = (j3 >> 3) & 63, e = j3 & 7;
            int c_tile = tile >> 2, ks = tile & 3;
            int c = c_tile * 16 + (l & 15);
            int k = ks * 32 + (l >> 4) * 8 + e;
            wof[j3] = f2bf(Wo[k * C_ + c]);
        }
    }
    if (blockIdx.x == 0) {      // build cnt[24][32] once (shared by all attn blocks)
        __shared__ int scnt[T_ * 32];
        for (int j = threadIdx.x; j < T_ * 32; j += 256) scnt[j] = 0;
        __syncthreads();
        for (int j = threadIdx.x; j < T_ * S_; j += 256) {
            int t = j / S_;
            atomicAdd(&scnt[t * 32 + idxs[j]], 1);
        }
        __syncthreads();
        for (int j = threadIdx.x; j < 192; j += 256) {
            unsigned v = (unsigned)scnt[4 * j] | ((unsigned)scnt[4 * j + 1] << 8)
                       | ((unsigned)scnt[4 * j + 2] << 16) | ((unsigned)scnt[4 * j + 3] << 24);
            ((unsigned*)cntg)[j] = v;
        }
    }
}

// ---------------- kernel 1: QKV projection via MFMA (x = query+tepe fused in staging)
__global__ __launch_bounds__(256) void k_qkv_mfma(
    const float* __restrict__ query, const float* __restrict__ tepe,
    const short* __restrict__ wqkvf,
    short* __restrict__ Q, short* __restrict__ K, short* __restrict__ V) {
    __shared__ __align__(16) short xs[BM * C_];
    int tid = threadIdx.x;
    int r0 = blockIdx.x * BM;
    {
        int row = tid >> 3;                 // 0..31
        int cb = (tid & 7) * 16;
        int gr = r0 + row;
        int t = gr % T_;
        int b = gr / (N_ * T_);
        const float* qsrc = query + (size_t)gr * C_ + cb;
        const float* tsrc = tepe + (size_t)(b * T_ + t) * C_ + cb;
        int swz0 = (row & 7) << 3;
#pragma unroll
        for (int i = 0; i < 4; i++) {
            float4 q4 = *(const float4*)(qsrc + 4 * i);
            float4 t4 = *(const float4*)(tsrc + 4 * i);
            short4_ sv;
            sv.x = f2bf(q4.x + t4.x); sv.y = f2bf(q4.y + t4.y);
            sv.z = f2bf(q4.z + t4.z); sv.w = f2bf(q4.w + t4.w);
            *(short4_*)&xs[(row * C_ + cb + 4 * i) ^ swz0] = sv;
        }
    }
    __syncthreads();
    int w = tid >> 6, l = tid & 63;
    int lr = l & 15, lk = l >> 4;
    int swz = (lr & 7) << 3;                // row-tile-invariant swizzle
    short8 bx[2][4];
#pragma unroll
    for (int rt = 0; rt < 2; rt++)
#pragma unroll
        for (int ks = 0; ks < 4; ks++)
            bx[rt][ks] = *(const short8*)&xs[((rt * 16 + lr) * C_ + ks * 32 + lk * 8) ^ swz];
    size_t base[2];
#pragma unroll
    for (int rt = 0; rt < 2; rt++) {
        int gr = r0 + rt * 16 + lr;
        int t = gr % T_;
        int n = (gr / T_) % N_;
        int b = gr / (N_ * T_);
        base[rt] = ((size_t)b * H_ * N_ + n) * (T_ * D_) + t * D_;
    }
#pragma unroll
    for (int jt = 0; jt < 6; jt++) {
        int ctile = w * 6 + jt;                 // c-tile index 0..23
        const short* ap = wqkvf + (size_t)ctile * 2048 + l * 8;
        short8 acur[4];
#pragma unroll
        for (int ks = 0; ks < 4; ks++) acur[ks] = *(const short8*)(ap + ks * 512);
        f32x4 acc[2] = {{0.f, 0.f, 0.f, 0.f}, {0.f, 0.f, 0.f, 0.f}};
#pragma unroll
        for (int ks = 0; ks < 4; ks++) {
#pragma unroll
            for (int rt = 0; rt < 2; rt++)
                acc[rt] = __builtin_amdgcn_mfma_f32_16x16x32_bf16(acur[ks], bx[rt][ks], acc[rt], 0, 0, 0);
        }
        int c0 = ctile * 16 + lk * 4;
        int m = c0 >> 7;
        int c = c0 & (C_ - 1);
        int h = c >> 4, d = c & 15;
        short* dst = (m == 0) ? Q : (m == 1) ? K : V;
#pragma unroll
        for (int rt = 0; rt < 2; rt++) {
            short4_ sv;
            sv.x = f2bf(acc[rt][0]); sv.y = f2bf(acc[rt][1]);
            sv.z = f2bf(acc[rt][2]); sv.w = f2bf(acc[rt][3]);
            *(short4_*)&dst[base[rt] + (size_t)h * (N_ * T_ * D_) + d] = sv;
        }
    }
}

// ---------------- kernel 2: attention, 4 units per 256-thread block (1 wave/unit)
// T5: setprio(1) around MFMA clusters — independent per-wave units give the CU
// scheduler wave-role diversity, where setprio measured +4-7% (guide m191).
__global__ __launch_bounds__(256) void k_attn(
    const short* __restrict__ Q, const short* __restrict__ K, const short* __restrict__ V,
    const unsigned char* __restrict__ cntg, short* __restrict__ ctx) {
    __shared__ __align__(16) short Qbf[4][32 * 24], Kbf[4][32 * 24];
    __shared__ __align__(16) short Vt[4][16 * 40];       // [d][t2], cols 24-31 zeroed
    __shared__ __align__(16) short Pbf[4][32 * 40];      // attn weights, cols 24-31 zeroed
    __shared__ unsigned char cntS[T_ * 32];              // shared by all 4 units
    __shared__ float Mv[4][T_];
    __shared__ int keepS[4][T_];
    __shared__ float meanVs[4][D_];
    int tid = threadIdx.x;
    int wid = tid >> 6, l = tid & 63;
    int e = blockIdx.x * 4 + wid;
    const short* qb = Q + (size_t)e * (T_ * D_);
    const short* kb = K + (size_t)e * (T_ * D_);
    const short* vb = V + (size_t)e * (T_ * D_);
    if (l < 48) {
        int t = l >> 1, hf = l & 1;
        *(short8*)&Qbf[wid][t * 24 + hf * 8] = *(const short8*)(qb + t * 16 + hf * 8);
        *(short8*)&Kbf[wid][t * 24 + hf * 8] = *(const short8*)(kb + t * 16 + hf * 8);
    }
    for (int i = l; i < 96; i += 64) {
        int t = i >> 2, c4 = i & 3;
        short4_ v = *(const short4_*)(vb + t * 16 + c4 * 4);
        Vt[wid][(c4 * 4 + 0) * 40 + t] = v.x;
        Vt[wid][(c4 * 4 + 1) * 40 + t] = v.y;
        Vt[wid][(c4 * 4 + 2) * 40 + t] = v.z;
        Vt[wid][(c4 * 4 + 3) * 40 + t] = v.w;
    }
    for (int i = l; i < 128; i += 64) {       // zero Vt cols 24-31
        int d = i >> 3, c = 24 + (i & 7);
        Vt[wid][d * 40 + c] = 0;
    }
    if (tid < 192) ((int*)cntS)[tid] = ((const int*)cntg)[tid];
    __syncthreads();
    if (l >= 48) {
        int d = l - 48;
        float s = 0.f;
        for (int t = 0; t < T_; t++) s += bf2f(Vt[wid][d * 40 + t]);
        meanVs[wid][d] = s * (1.0f / T_);
    }
    int lr = l & 15, lk = l >> 4;
    short8 zz = {};
    short8 kf0 = zz, kf1 = zz, qf0 = zz, qf1 = zz;
    if (lk < 2) {
        kf0 = *(const short8*)&Kbf[wid][lr * 24 + lk * 8];
        kf1 = *(const short8*)&Kbf[wid][(16 + lr) * 24 + lk * 8];
        qf0 = *(const short8*)&Qbf[wid][lr * 24 + lk * 8];
        qf1 = *(const short8*)&Qbf[wid][(16 + lr) * 24 + lk * 8];
    }
    f32x4 zf = {0.f, 0.f, 0.f, 0.f};
    __builtin_amdgcn_s_setprio(1);
    f32x4 s00 = __builtin_amdgcn_mfma_f32_16x16x32_bf16(kf0, qf0, zf, 0, 0, 0);
    f32x4 s01 = __builtin_amdgcn_mfma_f32_16x16x32_bf16(kf1, qf0, zf, 0, 0, 0);
    f32x4 s10 = __builtin_amdgcn_mfma_f32_16x16x32_bf16(kf0, qf1, zf, 0, 0, 0);
    f32x4 s11 = __builtin_amdgcn_mfma_f32_16x16x32_bf16(kf1, qf1, zf, 0, 0, 0);
    __builtin_amdgcn_s_setprio(0);
#pragma unroll
    for (int rt = 0; rt < 2; rt++) {
        int t = rt * 16 + lr;
        int tt = (t < T_) ? t : 0;
        f32x4 c0 = rt ? s10 : s00;
        f32x4 c1 = rt ? s11 : s01;
        float mx = -1e30f, sm = 0.f;
#pragma unroll
        for (int i = 0; i < 4; i++) {
            int cA = cntS[tt * 32 + lk * 4 + i];
            if (cA) { mx = fmaxf(mx, c0[i]); sm += (float)cA * c0[i]; }
        }
        if (lk < 2) {
#pragma unroll
            for (int i = 0; i < 4; i++) {
                int cB = cntS[tt * 32 + 16 + lk * 4 + i];
                if (cB) { mx = fmaxf(mx, c1[i]); sm += (float)cB * c1[i]; }
            }
        }
        mx = fmaxf(mx, __shfl_xor(mx, 16));
        mx = fmaxf(mx, __shfl_xor(mx, 32));
        sm += __shfl_xor(sm, 16);
        sm += __shfl_xor(sm, 32);
        if (lk == 0 && t < T_) Mv[wid][t] = mx - sm * (1.0f / S_);
    }
    __syncthreads();
    if (l < T_) {
        float mt = Mv[wid][l];
        int cnt2 = 0;
        for (int t2 = 0; t2 < T_; t2++) {
            float m2 = Mv[wid][t2];
            cnt2 += (m2 > mt) || (m2 == mt && t2 < l);
        }
        keepS[wid][l] = (cnt2 < U_) ? 1 : 0;
    }
#pragma unroll
    for (int rt = 0; rt < 2; rt++) {
        f32x4 c0 = rt ? s10 : s00;
        f32x4 c1 = rt ? s11 : s01;
        float lm = fmaxf(fmaxf(c0[0], c0[1]), fmaxf(c0[2], c0[3]));
        if (lk < 2) lm = fmaxf(lm, fmaxf(fmaxf(c1[0], c1[1]), fmaxf(c1[2], c1[3])));
        lm = fmaxf(lm, __shfl_xor(lm, 16));
        lm = fmaxf(lm, __shfl_xor(lm, 32));
        float e0[4], e1[4];
        float ls = 0.f;
#pragma unroll
        for (int i = 0; i < 4; i++) { e0[i] = __expf(0.25f * (c0[i] - lm)); ls += e0[i]; }
#pragma unroll
        for (int i = 0; i < 4; i++) { e1[i] = (lk < 2) ? __expf(0.25f * (c1[i] - lm)) : 0.f; ls += e1[i]; }
        ls += __shfl_xor(ls, 16);
        ls += __shfl_xor(ls, 32);
        float inv = 1.0f / ls;
        short4_ w0, w1;
        w0.x = f2bf(e0[0] * inv); w0.y = f2bf(e0[1] * inv);
        w0.z = f2bf(e0[2] * inv); w0.w = f2bf(e0[3] * inv);
        w1.x = f2bf(e1[0] * inv); w1.y = f2bf(e1[1] * inv);
        w1.z = f2bf(e1[2] * inv); w1.w = f2bf(e1[3] * inv);
        int trow = rt * 16 + lr;
        *(short4_*)&Pbf[wid][trow * 40 + lk * 4] = w0;
        *(short4_*)&Pbf[wid][trow * 40 + 16 + lk * 4] = w1;   // lk>=2 writes zeros
    }
    __syncthreads();
    short8 vf = *(const short8*)&Vt[wid][lr * 40 + lk * 8];
    short8 pf0 = *(const short8*)&Pbf[wid][lr * 40 + lk * 8];
    short8 pf1 = *(const short8*)&Pbf[wid][(16 + lr) * 40 + lk * 8];
    __builtin_amdgcn_s_setprio(1);
    f32x4 u0 = __builtin_amdgcn_mfma_f32_16x16x32_bf16(vf, pf0, zf, 0, 0, 0);
    f32x4 u1 = __builtin_amdgcn_mfma_f32_16x16x32_bf16(vf, pf1, zf, 0, 0, 0);
    __builtin_amdgcn_s_setprio(0);
    int b = e / (H_ * N_);
    int h = (e / N_) % H_;
    int n = e % N_;
    float4 mv4 = *(const float4*)&meanVs[wid][lk * 4];
#pragma unroll
    for (int rt = 0; rt < 2; rt++) {
        int t = rt * 16 + lr;
        if (t < T_) {
            f32x4 u = rt ? u1 : u0;
            float4 o;
            if (keepS[wid][t]) { o.x = u[0]; o.y = u[1]; o.z = u[2]; o.w = u[3]; }
            else o = mv4;
            short4_ sv;
            sv.x = f2bf(o.x); sv.y = f2bf(o.y); sv.z = f2bf(o.z); sv.w = f2bf(o.w);
            *(short4_*)&ctx[((size_t)(b * N_ + n) * T_ + t) * C_ + h * D_ + lk * 4] = sv;
        }
    }
}

// ---------------- kernel 3: fused tail (round-14 champion + T5 setprio).
// 3 blocks/CU at different phases -> wave-role diversity on each SIMD -> T5's
// precondition holds (guide m218b/m224). launch_bounds min-waves MUST stay 4:
// declaring 6 caps VGPR at 85 -> 40-VGPR spill collapse (rounds 11 & 13).
__global__ __launch_bounds__(256, 4) void k_tail(
    const short* __restrict__ ctx, const short* __restrict__ wof, const float* __restrict__ bo,
    const float* __restrict__ query, const float* __restrict__ tepe,
    const float* __restrict__ g1, const float* __restrict__ b1,
    const short* __restrict__ w1f, const float* __restrict__ b1f,
    const short* __restrict__ w2f, const float* __restrict__ b2f,
    const float* __restrict__ g2, const float* __restrict__ b2ln,
    float* __restrict__ out) {
    __shared__ __align__(16) char smem[25088];
    float (*xf)[132] = (float(*)[132])smem;             // phases 0-2
    short* hbf = (short*)smem;                          // phases 3-6, row stride 256
    float (*yf)[132] = (float(*)[132])smem;             // phases 7-8
    short* cbf = (short*)(smem + 16896);                // phases 0-1
    short* x1bf = (short*)(smem + 16896);               // phases 2-7 (cbf dead)
    int tid = threadIdx.x;
    int r0 = blockIdx.x * BMT;
    // ---- phase 0: stage ctx -> cbf, query+tepe -> xf
    {
        int row = tid >> 3;                 // 0..31
        int cb = (tid & 7) * 16;
        int gr = r0 + row;
        int t = gr % T_;
        int b = gr / (N_ * T_);
        const short* csrc = ctx + (size_t)gr * C_ + cb;
        const float* qsrc = query + (size_t)gr * C_ + cb;
        const float* tsrc = tepe + (size_t)(b * T_ + t) * C_ + cb;
        int swz0 = (row & 7) << 3;
        *(short8*)&cbf[(row * C_ + cb) ^ swz0] = *(const short8*)csrc;
        *(short8*)&cbf[(row * C_ + cb + 8) ^ swz0] = *(const short8*)(csrc + 8);
#pragma unroll
        for (int i = 0; i < 4; i++) {
            float4 q4 = *(const float4*)(qsrc + 4 * i);
            float4 t4 = *(const float4*)(tsrc + 4 * i);
            float4 xr;
            xr.x = q4.x + t4.x; xr.y = q4.y + t4.y;
            xr.z = q4.z + t4.z; xr.w = q4.w + t4.w;
            *(float4*)&xf[row][cb + 4 * i] = xr;
        }
    }
    __syncthreads();
    int w = tid >> 6, l = tid & 63;
    int lr = l & 15, lk = l >> 4;
    int swz = (lr & 7) << 3;
    // ---- phase 1: Wo GEMM; wave w owns c-tiles {2w, 2w+1} x both row-tiles
    {
#pragma unroll
        for (int ct = 0; ct < 2; ct++) {
            int c_tile = w * 2 + ct;
            const short* ap = wof + (size_t)c_tile * 2048 + l * 8;
            short8 acur[4];
#pragma unroll
            for (int ks = 0; ks < 4; ks++) acur[ks] = *(const short8*)(ap + ks * 512);
            f32x4 acc[2] = {{0.f, 0.f, 0.f, 0.f}, {0.f, 0.f, 0.f, 0.f}};
            __builtin_amdgcn_s_setprio(1);
#pragma unroll
            for (int ks = 0; ks < 4; ks++) {
#pragma unroll
                for (int rt = 0; rt < 2; rt++) {
                    short8 bc = *(const short8*)&cbf[((rt * 16 + lr) * C_ + ks * 32 + lk * 8) ^ swz];
                    acc[rt] = __builtin_amdgcn_mfma_f32_16x16x32_bf16(acur[ks], bc, acc[rt], 0, 0, 0);
                }
            }
            __builtin_amdgcn_s_setprio(0);
            int cc = c_tile * 16 + lk * 4;
            float4 bias = *(const float4*)(bo + cc);
#pragma unroll
            for (int rt = 0; rt < 2; rt++) {
                int rr = rt * 16 + lr;
                float4 res = *(const float4*)&xf[rr][cc];
                float4 o;
                o.x = acc[rt][0] + bias.x + res.x;
                o.y = acc[rt][1] + bias.y + res.y;
                o.z = acc[rt][2] + bias.z + res.z;
                o.w = acc[rt][3] + bias.w + res.w;
                *(float4*)&xf[rr][cc] = o;
            }
        }
    }
    __syncthreads();
    // ---- phase 2: LN1 -> x1bf (bf16, swizzled; cbf dead)
    {
        int r = tid >> 3;
        int q = tid & 7;
        int cb = q * 16;
        float vals[16];
        float s = 0.f;
#pragma unroll
        for (int i = 0; i < 16; i++) { vals[i] = xf[r][cb + i]; s += vals[i]; }
        s += __shfl_xor(s, 1, 8);
        s += __shfl_xor(s, 2, 8);
        s += __shfl_xor(s, 4, 8);
        float mean = s * (1.f / C_);
        float vv = 0.f;
#pragma unroll
        for (int i = 0; i < 16; i++) { float d = vals[i] - mean; vv += d * d; }
        vv += __shfl_xor(vv, 1, 8);
        vv += __shfl_xor(vv, 2, 8);
        vv += __shfl_xor(vv, 4, 8);
        float rstd = rsqrtf(vv * (1.f / C_) + 1e-5f);
        short8 o0, o1;
#pragma unroll
        for (int i = 0; i < 8; i++) {
            o0[i] = f2bf((vals[i] - mean) * rstd * g1[cb + i] + b1[cb + i]);
            o1[i] = f2bf((vals[8 + i] - mean) * rstd * g1[cb + 8 + i] + b1[cb + 8 + i]);
        }
        int swz0 = (r & 7) << 3;
        *(short8*)&x1bf[(r * C_ + cb) ^ swz0] = o0;
        *(short8*)&x1bf[(r * C_ + cb + 8) ^ swz0] = o1;
    }
    __syncthreads();    // xf dead from here; hbf may overwrite R1
    // ---- phases 3-6: FF in two K-half passes (hbf = 16 KB, j-half at a time)
    f32x4 acc2[2][2] = {{{0.f, 0.f, 0.f, 0.f}, {0.f, 0.f, 0.f, 0.f}},
                        {{0.f, 0.f, 0.f, 0.f}, {0.f, 0.f, 0.f, 0.f}}};
    for (int p = 0; p < 2; p++) {
        {
            short8 bx[2][4];
#pragma unroll
            for (int rt = 0; rt < 2; rt++)
#pragma unroll
                for (int ks = 0; ks < 4; ks++)
                    bx[rt][ks] = *(const short8*)&x1bf[((rt * 16 + lr) * C_ + ks * 32 + lk * 8) ^ swz];
#pragma unroll
            for (int jt = 0; jt < 4; jt++) {
                int jtile = p * 16 + w * 4 + jt;      // global jtile 0..31
                const short* ap = w1f + (size_t)jtile * 2048 + l * 8;
                short8 acur[4];
#pragma unroll
                for (int ks = 0; ks < 4; ks++) acur[ks] = *(const short8*)(ap + ks * 512);
                f32x4 acc[2] = {{0.f, 0.f, 0.f, 0.f}, {0.f, 0.f, 0.f, 0.f}};
                __builtin_amdgcn_s_setprio(1);
#pragma unroll
                for (int ks = 0; ks < 4; ks++) {
#pragma unroll
                    for (int rt = 0; rt < 2; rt++)
                        acc[rt] = __builtin_amdgcn_mfma_f32_16x16x32_bf16(acur[ks], bx[rt][ks], acc[rt], 0, 0, 0);
                }
                __builtin_amdgcn_s_setprio(0);
                int j0g = jtile * 16 + lk * 4;        // global j for bias
                int j0l = (w * 4 + jt) * 16 + lk * 4; // local j for hbf
                float4 bias = *(const float4*)(b1f + j0g);
#pragma unroll
                for (int rt = 0; rt < 2; rt++) {
                    int rr = rt * 16 + lr;
                    short4_ hv;
                    hv.x = f2bf(fmaxf(acc[rt][0] + bias.x, 0.f));
                    hv.y = f2bf(fmaxf(acc[rt][1] + bias.y, 0.f));
                    hv.z = f2bf(fmaxf(acc[rt][2] + bias.z, 0.f));
                    hv.w = f2bf(fmaxf(acc[rt][3] + bias.w, 0.f));
                    *(short4_*)&hbf[(rr * 256 + j0l) ^ swz] = hv;
                }
            }
        }
        __syncthreads();
        __builtin_amdgcn_s_setprio(1);
#pragma unroll 2
        for (int ks = 0; ks < 8; ks++) {
#pragma unroll
            for (int ct = 0; ct < 2; ct++) {
                short8 aw = *(const short8*)(w2f + ((size_t)((w * 2 + ct) * 16 + p * 8 + ks)) * 512 + l * 8);
#pragma unroll
                for (int rt = 0; rt < 2; rt++) {
                    short8 hx = *(const short8*)&hbf[((rt * 16 + lr) * 256 + ks * 32 + lk * 8) ^ swz];
                    acc2[ct][rt] = __builtin_amdgcn_mfma_f32_16x16x32_bf16(aw, hx, acc2[ct][rt], 0, 0, 0);
                }
            }
        }
        __builtin_amdgcn_s_setprio(0);
        __syncthreads();
    }
    // ---- phase 7: y2 = acc2 + bias + residual(x1bf) -> yf
    {
#pragma unroll
        for (int ct = 0; ct < 2; ct++) {
            int cc = (w * 2 + ct) * 16 + lk * 4;
            float4 bias2 = *(const float4*)(b2f + cc);
#pragma unroll
            for (int rt = 0; rt < 2; rt++) {
                int rr = rt * 16 + lr;
                short4_ rb = *(const short4_*)&x1bf[(rr * C_ + cc) ^ swz];
                float4 o;
                o.x = acc2[ct][rt][0] + bias2.x + bf2f(rb.x);
                o.y = acc2[ct][rt][1] + bias2.y + bf2f(rb.y);
                o.z = acc2[ct][rt][2] + bias2.z + bf2f(rb.z);
                o.w = acc2[ct][rt][3] + bias2.w + bf2f(rb.w);
                *(float4*)&yf[rr][cc] = o;
            }
        }
    }
    __syncthreads();
    // ---- phase 8: LN2 + store
    {
        int r = tid >> 3;
        int q = tid & 7;
        int cb = q * 16;
        float vals[16];
        float s = 0.f;
#pragma unroll
        for (int i = 0; i < 16; i++) { vals[i] = yf[r][cb + i]; s += vals[i]; }
        s += __shfl_xor(s, 1, 8);
        s += __shfl_xor(s, 2, 8);
        s += __shfl_xor(s, 4, 8);
        float mean = s * (1.f / C_);
        float vv = 0.f;
#pragma unroll
        for (int i = 0; i < 16; i++) { float d = vals[i] - mean; vv += d * d; }
        vv += __shfl_xor(vv, 1, 8);
        vv += __shfl_xor(vv, 2, 8);
        vv += __shfl_xor(vv, 4, 8);
        float rstd = rsqrtf(vv * (1.f / C_) + 1e-5f);
        float* op = out + (size_t)(r0 + r) * C_ + cb;
#pragma unroll
        for (int i4 = 0; i4 < 4; i4++) {
            float4 gv = *(const float4*)(g2 + cb + 4 * i4);
            float4 bv = *(const float4*)(b2ln + cb + 4 * i4);
            float4 ov;
            ov.x = (vals[4 * i4 + 0] - mean) * rstd * gv.x + bv.x;
            ov.y = (vals[4 * i4 + 1] - mean) * rstd * gv.y + bv.y;
            ov.z = (vals[4 * i4 + 2] - mean) * rstd * gv.z + bv.z;
            ov.w = (vals[4 * i4 + 3] - mean) * rstd * gv.w + bv.w;
            *(float4*)(op + 4 * i4) = ov;
        }
    }
}

extern "C" void kernel_launch(void* const* d_in, const int* in_sizes, int n_in,
                              void* d_out, int out_size, void* d_ws, size_t ws_size,
                              hipStream_t stream) {
    const float* query = (const float*)d_in[2];
    const int* time_enc = (const int*)d_in[4];
    const int* index_sample = (const int*)d_in[5];
    const float* e_min = (const float*)d_in[6];
    const float* e_hr  = (const float*)d_in[7];
    const float* e_wd  = (const float*)d_in[8];
    const float* e_mo  = (const float*)d_in[9];
    const float* e_yr  = (const float*)d_in[10];
    const float* Wq = (const float*)d_in[11];
    const float* Wk = (const float*)d_in[12];
    const float* Wv = (const float*)d_in[13];
    const float* Wo = (const float*)d_in[14];
    const float* bo = (const float*)d_in[15];
    const float* ffw1 = (const float*)d_in[16];
    const float* ffb1 = (const float*)d_in[17];
    const float* ffw2 = (const float*)d_in[18];
    const float* ffb2 = (const float*)d_in[19];
    const float* ln1g = (const float*)d_in[20];
    const float* ln1b = (const float*)d_in[21];
    const float* ln2g = (const float*)d_in[22];
    const float* ln2b = (const float*)d_in[23];

    float* ws = (float*)d_ws;
    float* tepe = ws;                     // TEPE_N floats
    float* region1 = ws + TEPE_N;         // NX floats: bf16 Q
    float* region2 = region1 + NX;        // NX floats: bf16 K (1st half) + w1f/w2f/wof (2nd half)
    float* region3 = region2 + NX;        // NX floats: bf16 V
    float* region4 = region3 + NX;        // NX floats: bf16 ctx + wqkvf + cntg

    short* Qb = (short*)region1;
    short* Kb = (short*)region2;
    short* Vb = (short*)region3;
    short* ctxb = (short*)region4;
    short* wqkvf = (short*)region4 + NX;        // dead after qkv
    unsigned char* cntg = (unsigned char*)((short*)region4 + NX + 49152);  // 768 B
    short* w1f = (short*)region2 + NX;          // region2 second half (K uses first; r19-proven)
    short* w2f = w1f + C_ * FF;
    short* wof = w2f + C_ * FF;

    k_prep<<<dim3(PREP_N / 256), dim3(256), 0, stream>>>(
        time_enc, e_min, e_hr, e_wd, e_mo, e_yr, tepe, index_sample, cntg,
        Wq, Wk, Wv, wqkvf, ffw1, ffw2, Wo, w1f, w2f, wof);
    k_qkv_mfma<<<dim3(NBLK_MM), dim3(256), 0, stream>>>(
        query, tepe, wqkvf, Qb, Kb, Vb);
    k_attn<<<dim3(NUNIT / 4), dim3(256), 0, stream>>>(
        Qb, Kb, Vb, cntg, ctxb);
    k_tail<<<dim3(NBLK_T), dim3(256), 0, stream>>>(
        ctxb, wof, bo, query, tepe, ln1g, ln1b,
        w1f, ffb1, w2f, ffb2, ln2g, ln2b, (float*)d_out);
}